// Round 1
// baseline (1255.660 us; speedup 1.0000x reference)
//
#include <hip/hip_runtime.h>
#include <math.h>

#define HID 64
#define IN_DIM 128
#define OUTC 8
#define TNODES 32   // nodes per block in dense kernels
#define PAD 68      // 64+4 floats, padded row stride for LDS

static __device__ __forceinline__ float dot4(float4 a, float4 b){
  return fmaf(a.x,b.x, fmaf(a.y,b.y, fmaf(a.z,b.z, a.w*b.w)));
}

__global__ void k_zero(int* __restrict__ p, int n){
  int i = blockIdx.x*blockDim.x + threadIdx.x;
  if(i<n) p[i]=0;
}

__global__ void k_hist(const int* __restrict__ dst, int* __restrict__ cnt, int E){
  int i = blockIdx.x*blockDim.x + threadIdx.x;
  if(i<E) atomicAdd(&cnt[dst[i]], 1);
}

// per-chunk exclusive scan of cnt -> rowptr(chunk-local), chunk sums -> partials
__global__ void k_scan1(const int* __restrict__ cnt, int* __restrict__ rowptr,
                        int* __restrict__ partials, int n){
  __shared__ int s[256];
  int tid = threadIdx.x; int gid = blockIdx.x*256 + tid;
  int v = (gid<n)? cnt[gid] : 0;
  s[tid] = v; __syncthreads();
  #pragma unroll
  for(int off=1; off<256; off<<=1){
    int t = (tid>=off)? s[tid-off] : 0; __syncthreads();
    s[tid] += t; __syncthreads();
  }
  if(gid<n) rowptr[gid] = s[tid] - v;       // exclusive within chunk
  if(tid==255) partials[blockIdx.x] = s[255];
}

__global__ void k_scan2(int* __restrict__ partials, int np){
  __shared__ int s[256];
  int tid = threadIdx.x;
  int v = (tid<np)? partials[tid] : 0;
  s[tid] = v; __syncthreads();
  #pragma unroll
  for(int off=1; off<256; off<<=1){
    int t = (tid>=off)? s[tid-off] : 0; __syncthreads();
    s[tid] += t; __syncthreads();
  }
  if(tid<np) partials[tid] = s[tid] - v;    // exclusive
}

__global__ void k_scan3(int* __restrict__ rowptr, const int* __restrict__ partials,
                        int* __restrict__ nextpos, int n, int E){
  int gid = blockIdx.x*256 + threadIdx.x;
  if(gid<n){
    int v = rowptr[gid] + partials[blockIdx.x];
    rowptr[gid] = v;
    nextpos[gid] = v;
  }
  if(gid==0) rowptr[n] = E;
}

__global__ void k_scatter(const int* __restrict__ src, const int* __restrict__ dst,
                          const float* __restrict__ d, const float* __restrict__ wr,
                          const float* __restrict__ wi, int* __restrict__ nextpos,
                          int* __restrict__ srcS, float* __restrict__ erS,
                          float* __restrict__ eiS, int E){
  int i = blockIdx.x*blockDim.x + threadIdx.x;
  if(i>=E) return;
  int s = src[i], t = dst[i];
  float dd = d[t]*d[s];
  int p = atomicAdd(&nextpos[t], 1);
  srcS[p] = s;
  erS[p] = dd*wr[i];
  eiS[p] = dd*wi[i];
}

// h[N,128] -> hr,hi = relu(h @ W.T + b), W:[64,128]
__global__ __launch_bounds__(256) void k_transform1(
    const float* __restrict__ h, const float* __restrict__ Wr, const float* __restrict__ br,
    const float* __restrict__ Wi, const float* __restrict__ bi,
    float* __restrict__ hr, float* __restrict__ hi_, int N){
  __shared__ float sWr[64*PAD], sWi[64*PAD], sX[TNODES*PAD];
  int tid = threadIdx.x;
  int g = tid>>6, o = tid&63;
  int node0 = blockIdx.x*TNODES;
  float accR[8], accI[8];
  #pragma unroll
  for(int m=0;m<8;m++){ accR[m]=0.f; accI[m]=0.f; }
  for(int half=0; half<2; half++){
    #pragma unroll
    for(int t=0;t<4;t++){
      int f4 = tid + t*256; int o2 = f4>>4, kc = f4&15;
      *(float4*)&sWr[o2*PAD + kc*4] = *(const float4*)&Wr[o2*IN_DIM + half*64 + kc*4];
      *(float4*)&sWi[o2*PAD + kc*4] = *(const float4*)&Wi[o2*IN_DIM + half*64 + kc*4];
    }
    #pragma unroll
    for(int t=0;t<2;t++){
      int f4 = tid + t*256; int nl = f4>>4, kc = f4&15;
      int node = node0 + nl;
      float4 x = make_float4(0.f,0.f,0.f,0.f);
      if(node<N) x = *(const float4*)&h[node*IN_DIM + half*64 + kc*4];
      *(float4*)&sX[nl*PAD + kc*4] = x;
    }
    __syncthreads();
    #pragma unroll
    for(int jc=0;jc<16;jc++){
      float4 wr4 = *(const float4*)&sWr[o*PAD + jc*4];
      float4 wi4 = *(const float4*)&sWi[o*PAD + jc*4];
      #pragma unroll
      for(int m=0;m<8;m++){
        float4 x = *(const float4*)&sX[(g*8+m)*PAD + jc*4];
        accR[m] += dot4(x, wr4);
        accI[m] += dot4(x, wi4);
      }
    }
    __syncthreads();
  }
  float brv = br[o], biv = bi[o];
  #pragma unroll
  for(int m=0;m<8;m++){
    int node = node0 + g*8 + m;
    if(node<N){
      hr[node*HID+o]  = fmaxf(accR[m]+brv, 0.f);
      hi_[node*HID+o] = fmaxf(accI[m]+biv, 0.f);
    }
  }
}

// CSR gather aggregation: one wave per dst node, lane = hidden dim
__global__ __launch_bounds__(256) void k_agg(
    const int* __restrict__ rowptr, const int* __restrict__ srcS,
    const float* __restrict__ erS, const float* __restrict__ eiS,
    const float* __restrict__ hr, const float* __restrict__ hi_,
    float* __restrict__ zr, float* __restrict__ zi_, int N){
  int lane = threadIdx.x & 63;
  int node = (blockIdx.x*blockDim.x + threadIdx.x) >> 6;
  if(node>=N) return;
  int beg = rowptr[node], end = rowptr[node+1];
  float ar=0.f, ai=0.f;
  #pragma unroll 2
  for(int j=beg; j<end; j++){
    int s = srcS[j];
    float er = erS[j], ei = eiS[j];
    float xr = hr[s*HID+lane], xi = hi_[s*HID+lane];
    ar = fmaf(er, xr, ar); ar = fmaf(-ei, xi, ar);
    ai = fmaf(ei, xr, ai); ai = fmaf(er, xi, ai);
  }
  zr[node*HID+lane]  = ar;
  zi_[node*HID+lane] = ai;
}

// fused complex dense layer (both sub-GEMMs incl. the zrn->zin dependency)
__global__ __launch_bounds__(256) void k_dense(
    const float* __restrict__ W1, const float* __restrict__ b1,
    const float* __restrict__ W2, const float* __restrict__ b2,
    const float* __restrict__ zr, const float* __restrict__ zi_,
    float* __restrict__ hr, float* __restrict__ hi_, int N){
  __shared__ float sW1[64*PAD], sW2[64*PAD], sZR[TNODES*PAD], sZI[TNODES*PAD];
  int tid = threadIdx.x; int g = tid>>6, o = tid&63;
  int node0 = blockIdx.x*TNODES;
  #pragma unroll
  for(int t=0;t<4;t++){
    int f4 = tid + t*256; int o2 = f4>>4, kc = f4&15;
    *(float4*)&sW1[o2*PAD + kc*4] = *(const float4*)&W1[o2*HID + kc*4];
    *(float4*)&sW2[o2*PAD + kc*4] = *(const float4*)&W2[o2*HID + kc*4];
  }
  #pragma unroll
  for(int t=0;t<2;t++){
    int f4 = tid + t*256; int nl = f4>>4, kc = f4&15;
    int node = node0 + nl;
    float4 a = make_float4(0.f,0.f,0.f,0.f), b = a;
    if(node<N){
      a = *(const float4*)&zr[node*HID + kc*4];
      b = *(const float4*)&zi_[node*HID + kc*4];
    }
    *(float4*)&sZR[nl*PAD + kc*4] = a;
    *(float4*)&sZI[nl*PAD + kc*4] = b;
  }
  __syncthreads();
  float accA[8], accB[8], accC[8];
  #pragma unroll
  for(int m=0;m<8;m++){ accA[m]=0.f; accB[m]=0.f; accC[m]=0.f; }
  #pragma unroll
  for(int jc=0;jc<16;jc++){
    float4 w1 = *(const float4*)&sW1[o*PAD + jc*4];
    float4 w2 = *(const float4*)&sW2[o*PAD + jc*4];
    #pragma unroll
    for(int m=0;m<8;m++){
      float4 xr = *(const float4*)&sZR[(g*8+m)*PAD + jc*4];
      float4 xi = *(const float4*)&sZI[(g*8+m)*PAD + jc*4];
      accA[m] += dot4(xr, w1);
      accB[m] += dot4(xi, w2);
      accC[m] += dot4(xi, w1);
    }
  }
  float b1v = b1[o], b2v = b2[o];
  float zrn[8];
  #pragma unroll
  for(int m=0;m<8;m++) zrn[m] = accA[m] + b1v - accB[m] - b2v;
  __syncthreads();                       // everyone done reading sZR
  #pragma unroll
  for(int m=0;m<8;m++) sZR[(g*8+m)*PAD + o] = zrn[m];   // pre-relu zrn tile
  __syncthreads();
  float accD[8];
  #pragma unroll
  for(int m=0;m<8;m++) accD[m]=0.f;
  #pragma unroll
  for(int jc=0;jc<16;jc++){
    float4 w2 = *(const float4*)&sW2[o*PAD + jc*4];
    #pragma unroll
    for(int m=0;m<8;m++){
      float4 x = *(const float4*)&sZR[(g*8+m)*PAD + jc*4];
      accD[m] += dot4(x, w2);
    }
  }
  #pragma unroll
  for(int m=0;m<8;m++){
    int node = node0 + g*8 + m;
    if(node<N){
      float zin = accD[m] + b2v + accC[m] + b1v;
      hr[node*HID+o]  = fmaxf(zrn[m], 0.f);
      hi_[node*HID+o] = fmaxf(zin, 0.f);
    }
  }
}

// logits (128->8) + log_softmax; 8 lanes per node
__global__ __launch_bounds__(256) void k_final(
    const float* __restrict__ hr, const float* __restrict__ hi_,
    const float* __restrict__ t2W, const float* __restrict__ t2b,
    float* __restrict__ out, int N){
  __shared__ float sW[OUTC*132];
  int tid = threadIdx.x;
  {
    int o2 = tid>>5, kc = tid&31;   // 256 float4 = 8*128 floats exactly
    *(float4*)&sW[o2*132 + kc*4] = *(const float4*)&t2W[o2*128 + kc*4];
  }
  __syncthreads();
  int o = tid&7, nl = tid>>3;
  int node = blockIdx.x*32 + nl;
  float acc = 0.f;
  if(node<N){
    acc = t2b[o];
    #pragma unroll
    for(int jc=0;jc<16;jc++){
      float4 x = *(const float4*)&hr[node*HID + jc*4];
      float4 w = *(const float4*)&sW[o*132 + jc*4];
      acc += dot4(x,w);
    }
    #pragma unroll
    for(int jc=0;jc<16;jc++){
      float4 x = *(const float4*)&hi_[node*HID + jc*4];
      float4 w = *(const float4*)&sW[o*132 + 64 + jc*4];
      acc += dot4(x,w);
    }
  }
  float mx = acc;
  #pragma unroll
  for(int msk=4; msk>=1; msk>>=1) mx = fmaxf(mx, __shfl_xor(mx, msk, 8));
  float e = expf(acc - mx);
  float sm = e;
  #pragma unroll
  for(int msk=4; msk>=1; msk>>=1) sm += __shfl_xor(sm, msk, 8);
  if(node<N) out[node*OUTC+o] = (acc - mx) - logf(sm);
}

extern "C" void kernel_launch(void* const* d_in, const int* in_sizes, int n_in,
                              void* d_out, int out_size, void* d_ws, size_t ws_size,
                              hipStream_t stream) {
  const float* h      = (const float*)d_in[0];
  const float* d      = (const float*)d_in[1];
  const float* w_real = (const float*)d_in[2];
  const float* w_imag = (const float*)d_in[3];
  const float* t1rW   = (const float*)d_in[4];
  const float* t1rb   = (const float*)d_in[5];
  const float* t1iW   = (const float*)d_in[6];
  const float* t1ib   = (const float*)d_in[7];
  const float* W1     = (const float*)d_in[8];
  const float* b1     = (const float*)d_in[9];
  const float* W2     = (const float*)d_in[10];
  const float* b2     = (const float*)d_in[11];
  const float* t2W    = (const float*)d_in[12];
  const float* t2b    = (const float*)d_in[13];
  const int*   src    = (const int*)d_in[14];
  const int*   dst    = (const int*)d_in[15];
  const int N = in_sizes[1];
  const int E = in_sizes[2];
  const int nLayers = in_sizes[8] / (HID*HID);
  float* out = (float*)d_out;

  char* w = (char*)d_ws;
  size_t off = 0;
  auto alloc = [&](size_t bytes)->void*{
    void* p = (void*)(w + off);
    off += (bytes + 255) & ~(size_t)255;
    return p;
  };
  float* hr      = (float*)alloc((size_t)N*HID*4);
  float* hi      = (float*)alloc((size_t)N*HID*4);
  float* zr      = (float*)alloc((size_t)N*HID*4);
  float* zi      = (float*)alloc((size_t)N*HID*4);
  int*   rowptr  = (int*)alloc((size_t)(N+1)*4);
  int*   cnt     = (int*)alloc((size_t)N*4);
  int*   nextpos = (int*)alloc((size_t)N*4);
  int*   srcS    = (int*)alloc((size_t)E*4);
  float* erS     = (float*)alloc((size_t)E*4);
  float* eiS     = (float*)alloc((size_t)E*4);
  int*   partials= (int*)alloc(1024);

  int nChunks = (N+255)/256;
  int eBlocks = (E+255)/256;
  int nTiles  = (N+TNODES-1)/TNODES;
  int aggBlocks = (N+3)/4;   // 4 waves (nodes) per 256-thread block

  k_zero<<<nChunks, 256, 0, stream>>>(cnt, N);
  k_hist<<<eBlocks, 256, 0, stream>>>(dst, cnt, E);
  k_scan1<<<nChunks, 256, 0, stream>>>(cnt, rowptr, partials, N);
  k_scan2<<<1, 256, 0, stream>>>(partials, nChunks);
  k_scan3<<<nChunks, 256, 0, stream>>>(rowptr, partials, nextpos, N, E);
  k_scatter<<<eBlocks, 256, 0, stream>>>(src, dst, d, w_real, w_imag,
                                         nextpos, srcS, erS, eiS, E);
  k_transform1<<<nTiles, 256, 0, stream>>>(h, t1rW, t1rb, t1iW, t1ib, hr, hi, N);
  for(int i=0;i<nLayers;i++){
    k_agg<<<aggBlocks, 256, 0, stream>>>(rowptr, srcS, erS, eiS, hr, hi, zr, zi, N);
    k_dense<<<nTiles, 256, 0, stream>>>(W1 + (size_t)i*HID*HID, b1 + (size_t)i*HID,
                                        W2 + (size_t)i*HID*HID, b2 + (size_t)i*HID,
                                        zr, zi, hr, hi, N);
  }
  k_final<<<(N+31)/32, 256, 0, stream>>>(hr, hi, t2W, t2b, out, N);
}

// Round 2
// 430.228 us; speedup vs baseline: 2.9186x; 2.9186x over previous
//
#include <hip/hip_runtime.h>
#include <math.h>

#define HID 64
#define IN_DIM 128
#define OUTC 8
#define TNODES 32   // nodes per block in dense kernels
#define PAD 68      // 64+4 floats, padded row stride for LDS

static __device__ __forceinline__ float dot4(float4 a, float4 b){
  return fmaf(a.x,b.x, fmaf(a.y,b.y, fmaf(a.z,b.z, a.w*b.w)));
}

__global__ void k_zero(int* __restrict__ p, int n){
  int i = blockIdx.x*blockDim.x + threadIdx.x;
  if(i<n) p[i]=0;
}

__global__ void k_hist(const int* __restrict__ dst, int* __restrict__ cnt, int E){
  int i = blockIdx.x*blockDim.x + threadIdx.x;
  if(i<E) atomicAdd(&cnt[dst[i]], 1);
}

// per-chunk exclusive scan of cnt -> rowptr(chunk-local), chunk sums -> partials
__global__ void k_scan1(const int* __restrict__ cnt, int* __restrict__ rowptr,
                        int* __restrict__ partials, int n){
  __shared__ int s[256];
  int tid = threadIdx.x; int gid = blockIdx.x*256 + tid;
  int v = (gid<n)? cnt[gid] : 0;
  s[tid] = v; __syncthreads();
  #pragma unroll
  for(int off=1; off<256; off<<=1){
    int t = (tid>=off)? s[tid-off] : 0; __syncthreads();
    s[tid] += t; __syncthreads();
  }
  if(gid<n) rowptr[gid] = s[tid] - v;       // exclusive within chunk
  if(tid==255) partials[blockIdx.x] = s[255];
}

__global__ void k_scan2(int* __restrict__ partials, int np){
  __shared__ int s[256];
  int tid = threadIdx.x;
  int v = (tid<np)? partials[tid] : 0;
  s[tid] = v; __syncthreads();
  #pragma unroll
  for(int off=1; off<256; off<<=1){
    int t = (tid>=off)? s[tid-off] : 0; __syncthreads();
    s[tid] += t; __syncthreads();
  }
  if(tid<np) partials[tid] = s[tid] - v;    // exclusive
}

__global__ void k_scan3(int* __restrict__ rowptr, const int* __restrict__ partials,
                        int* __restrict__ nextpos, int n, int E){
  int gid = blockIdx.x*256 + threadIdx.x;
  if(gid<n){
    int v = rowptr[gid] + partials[blockIdx.x];
    rowptr[gid] = v;
    nextpos[gid] = v;
  }
  if(gid==0) rowptr[n] = E;
}

__global__ void k_scatter(const int* __restrict__ src, const int* __restrict__ dst,
                          const float* __restrict__ d, const float* __restrict__ wr,
                          const float* __restrict__ wi, int* __restrict__ nextpos,
                          int* __restrict__ srcS, float* __restrict__ erS,
                          float* __restrict__ eiS, int E){
  int i = blockIdx.x*blockDim.x + threadIdx.x;
  if(i>=E) return;
  int s = src[i], t = dst[i];
  float dd = d[t]*d[s];
  int p = atomicAdd(&nextpos[t], 1);
  srcS[p] = s;
  erS[p] = dd*wr[i];
  eiS[p] = dd*wi[i];
}

// h[N,128] -> hr,hi = relu(h @ W.T + b), W:[64,128]
// 256 thr = 32 lanes (outputs o, o+32) x 8 groups x 4 nodes
__global__ __launch_bounds__(256) void k_transform1(
    const float* __restrict__ h, const float* __restrict__ Wr, const float* __restrict__ br,
    const float* __restrict__ Wi, const float* __restrict__ bi,
    float* __restrict__ hr, float* __restrict__ hi_, int N){
  __shared__ float sWr[64*PAD], sWi[64*PAD], sX[TNODES*PAD];
  int tid = threadIdx.x;
  int o = tid & 31, grp = tid >> 5;
  int node0 = blockIdx.x*TNODES;
  float accR[2][4], accI[2][4];
  #pragma unroll
  for(int q=0;q<2;q++)
    #pragma unroll
    for(int m=0;m<4;m++){ accR[q][m]=0.f; accI[q][m]=0.f; }
  for(int half=0; half<2; half++){
    if(half) __syncthreads();   // protect LDS reuse across halves
    #pragma unroll
    for(int t=0;t<4;t++){
      int f4 = tid + t*256; int o2 = f4>>4, kc = f4&15;
      *(float4*)&sWr[o2*PAD + kc*4] = *(const float4*)&Wr[o2*IN_DIM + half*64 + kc*4];
      *(float4*)&sWi[o2*PAD + kc*4] = *(const float4*)&Wi[o2*IN_DIM + half*64 + kc*4];
    }
    #pragma unroll
    for(int t=0;t<2;t++){
      int f4 = tid + t*256; int nl = f4>>4, kc = f4&15;
      int node = node0 + nl;
      float4 x = make_float4(0.f,0.f,0.f,0.f);
      if(node<N) x = *(const float4*)&h[node*IN_DIM + half*64 + kc*4];
      *(float4*)&sX[nl*PAD + kc*4] = x;
    }
    __syncthreads();
    #pragma unroll 4
    for(int jc=0;jc<16;jc++){
      float4 wra = *(const float4*)&sWr[o*PAD + jc*4];
      float4 wrb = *(const float4*)&sWr[(o+32)*PAD + jc*4];
      float4 wia = *(const float4*)&sWi[o*PAD + jc*4];
      float4 wib = *(const float4*)&sWi[(o+32)*PAD + jc*4];
      #pragma unroll
      for(int m=0;m<4;m++){
        float4 x = *(const float4*)&sX[(grp*4+m)*PAD + jc*4];
        accR[0][m] += dot4(x, wra);
        accR[1][m] += dot4(x, wrb);
        accI[0][m] += dot4(x, wia);
        accI[1][m] += dot4(x, wib);
      }
    }
  }
  float bra = br[o], brb = br[o+32], bia = bi[o], bib = bi[o+32];
  #pragma unroll
  for(int m=0;m<4;m++){
    int node = node0 + grp*4 + m;
    if(node<N){
      hr[node*HID+o]     = fmaxf(accR[0][m]+bra, 0.f);
      hr[node*HID+o+32]  = fmaxf(accR[1][m]+brb, 0.f);
      hi_[node*HID+o]    = fmaxf(accI[0][m]+bia, 0.f);
      hi_[node*HID+o+32] = fmaxf(accI[1][m]+bib, 0.f);
    }
  }
}

// CSR gather aggregation: one wave per dst node, lane = hidden dim
__global__ __launch_bounds__(256) void k_agg(
    const int* __restrict__ rowptr, const int* __restrict__ srcS,
    const float* __restrict__ erS, const float* __restrict__ eiS,
    const float* __restrict__ hr, const float* __restrict__ hi_,
    float* __restrict__ zr, float* __restrict__ zi_, int N){
  int lane = threadIdx.x & 63;
  int node = (blockIdx.x*blockDim.x + threadIdx.x) >> 6;
  if(node>=N) return;
  int beg = rowptr[node], end = rowptr[node+1];
  float ar=0.f, ai=0.f;
  #pragma unroll 2
  for(int j=beg; j<end; j++){
    int s = srcS[j];
    float er = erS[j], ei = eiS[j];
    float xr = hr[s*HID+lane], xi = hi_[s*HID+lane];
    ar = fmaf(er, xr, ar); ar = fmaf(-ei, xi, ar);
    ai = fmaf(ei, xr, ai); ai = fmaf(er, xi, ai);
  }
  zr[node*HID+lane]  = ar;
  zi_[node*HID+lane] = ai;
}

// fused complex dense layer, register-lean multi-pass version.
// 256 thr = 32 lanes (outputs o, o+32) x 8 groups x 4 nodes
__global__ __launch_bounds__(256) void k_dense(
    const float* __restrict__ W1, const float* __restrict__ b1,
    const float* __restrict__ W2, const float* __restrict__ b2,
    const float* __restrict__ zr, const float* __restrict__ zi_,
    float* __restrict__ hr, float* __restrict__ hi_, int N){
  __shared__ float sW1[64*PAD], sW2[64*PAD], sZR[TNODES*PAD], sZI[TNODES*PAD];
  int tid = threadIdx.x;
  int o = tid & 31, grp = tid >> 5;
  int node0 = blockIdx.x*TNODES;
  #pragma unroll
  for(int t=0;t<4;t++){
    int f4 = tid + t*256; int o2 = f4>>4, kc = f4&15;
    *(float4*)&sW1[o2*PAD + kc*4] = *(const float4*)&W1[o2*HID + kc*4];
    *(float4*)&sW2[o2*PAD + kc*4] = *(const float4*)&W2[o2*HID + kc*4];
  }
  #pragma unroll
  for(int t=0;t<2;t++){
    int f4 = tid + t*256; int nl = f4>>4, kc = f4&15;
    int node = node0 + nl;
    float4 a = make_float4(0.f,0.f,0.f,0.f), b = a;
    if(node<N){
      a = *(const float4*)&zr[node*HID + kc*4];
      b = *(const float4*)&zi_[node*HID + kc*4];
    }
    *(float4*)&sZR[nl*PAD + kc*4] = a;
    *(float4*)&sZI[nl*PAD + kc*4] = b;
  }
  __syncthreads();

  // Pass A: accA = zr . W1^T
  float zrn[2][4];
  float accC[2][4];
  {
    float accA[2][4];
    #pragma unroll
    for(int q=0;q<2;q++)
      #pragma unroll
      for(int m=0;m<4;m++) accA[q][m]=0.f;
    #pragma unroll 4
    for(int jc=0;jc<16;jc++){
      float4 w1a = *(const float4*)&sW1[o*PAD + jc*4];
      float4 w1b = *(const float4*)&sW1[(o+32)*PAD + jc*4];
      #pragma unroll
      for(int m=0;m<4;m++){
        float4 xr = *(const float4*)&sZR[(grp*4+m)*PAD + jc*4];
        accA[0][m] += dot4(xr, w1a);
        accA[1][m] += dot4(xr, w1b);
      }
    }
    // Pass B/C: accB = zi . W2^T ; accC = zi . W1^T
    float accB[2][4];
    #pragma unroll
    for(int q=0;q<2;q++)
      #pragma unroll
      for(int m=0;m<4;m++){ accB[q][m]=0.f; accC[q][m]=0.f; }
    #pragma unroll 4
    for(int jc=0;jc<16;jc++){
      float4 w1a = *(const float4*)&sW1[o*PAD + jc*4];
      float4 w1b = *(const float4*)&sW1[(o+32)*PAD + jc*4];
      float4 w2a = *(const float4*)&sW2[o*PAD + jc*4];
      float4 w2b = *(const float4*)&sW2[(o+32)*PAD + jc*4];
      #pragma unroll
      for(int m=0;m<4;m++){
        float4 xi = *(const float4*)&sZI[(grp*4+m)*PAD + jc*4];
        accB[0][m] += dot4(xi, w2a);
        accB[1][m] += dot4(xi, w2b);
        accC[0][m] += dot4(xi, w1a);
        accC[1][m] += dot4(xi, w1b);
      }
    }
    float b1a = b1[o], b1b = b1[o+32], b2a = b2[o], b2b = b2[o+32];
    #pragma unroll
    for(int m=0;m<4;m++){
      zrn[0][m] = accA[0][m] + b1a - accB[0][m] - b2a;
      zrn[1][m] = accA[1][m] + b1b - accB[1][m] - b2b;
    }
  }
  __syncthreads();                 // all reads of sZR done
  #pragma unroll
  for(int m=0;m<4;m++){
    sZR[(grp*4+m)*PAD + o]      = zrn[0][m];   // pre-relu z_real_new tile
    sZR[(grp*4+m)*PAD + o + 32] = zrn[1][m];
  }
  __syncthreads();
  // Pass D: accD = zrn . W2^T
  float accD[2][4];
  #pragma unroll
  for(int q=0;q<2;q++)
    #pragma unroll
    for(int m=0;m<4;m++) accD[q][m]=0.f;
  #pragma unroll 4
  for(int jc=0;jc<16;jc++){
    float4 w2a = *(const float4*)&sW2[o*PAD + jc*4];
    float4 w2b = *(const float4*)&sW2[(o+32)*PAD + jc*4];
    #pragma unroll
    for(int m=0;m<4;m++){
      float4 x = *(const float4*)&sZR[(grp*4+m)*PAD + jc*4];
      accD[0][m] += dot4(x, w2a);
      accD[1][m] += dot4(x, w2b);
    }
  }
  float b1a = b1[o], b1b = b1[o+32], b2a = b2[o], b2b = b2[o+32];
  #pragma unroll
  for(int m=0;m<4;m++){
    int node = node0 + grp*4 + m;
    if(node<N){
      float zina = accD[0][m] + b2a + accC[0][m] + b1a;
      float zinb = accD[1][m] + b2b + accC[1][m] + b1b;
      hr[node*HID+o]     = fmaxf(zrn[0][m], 0.f);
      hr[node*HID+o+32]  = fmaxf(zrn[1][m], 0.f);
      hi_[node*HID+o]    = fmaxf(zina, 0.f);
      hi_[node*HID+o+32] = fmaxf(zinb, 0.f);
    }
  }
}

// logits (128->8) + log_softmax; 8 lanes per node
__global__ __launch_bounds__(256) void k_final(
    const float* __restrict__ hr, const float* __restrict__ hi_,
    const float* __restrict__ t2W, const float* __restrict__ t2b,
    float* __restrict__ out, int N){
  __shared__ float sW[OUTC*132];
  int tid = threadIdx.x;
  {
    int o2 = tid>>5, kc = tid&31;   // 256 float4 = 8*128 floats exactly
    *(float4*)&sW[o2*132 + kc*4] = *(const float4*)&t2W[o2*128 + kc*4];
  }
  __syncthreads();
  int o = tid&7, nl = tid>>3;
  int node = blockIdx.x*32 + nl;
  float acc = 0.f;
  if(node<N){
    acc = t2b[o];
    #pragma unroll
    for(int jc=0;jc<16;jc++){
      float4 x = *(const float4*)&hr[node*HID + jc*4];
      float4 w = *(const float4*)&sW[o*132 + jc*4];
      acc += dot4(x,w);
    }
    #pragma unroll
    for(int jc=0;jc<16;jc++){
      float4 x = *(const float4*)&hi_[node*HID + jc*4];
      float4 w = *(const float4*)&sW[o*132 + 64 + jc*4];
      acc += dot4(x,w);
    }
  }
  float mx = acc;
  #pragma unroll
  for(int msk=4; msk>=1; msk>>=1) mx = fmaxf(mx, __shfl_xor(mx, msk, 8));
  float e = expf(acc - mx);
  float sm = e;
  #pragma unroll
  for(int msk=4; msk>=1; msk>>=1) sm += __shfl_xor(sm, msk, 8);
  if(node<N) out[node*OUTC+o] = (acc - mx) - logf(sm);
}

extern "C" void kernel_launch(void* const* d_in, const int* in_sizes, int n_in,
                              void* d_out, int out_size, void* d_ws, size_t ws_size,
                              hipStream_t stream) {
  const float* h      = (const float*)d_in[0];
  const float* d      = (const float*)d_in[1];
  const float* w_real = (const float*)d_in[2];
  const float* w_imag = (const float*)d_in[3];
  const float* t1rW   = (const float*)d_in[4];
  const float* t1rb   = (const float*)d_in[5];
  const float* t1iW   = (const float*)d_in[6];
  const float* t1ib   = (const float*)d_in[7];
  const float* W1     = (const float*)d_in[8];
  const float* b1     = (const float*)d_in[9];
  const float* W2     = (const float*)d_in[10];
  const float* b2     = (const float*)d_in[11];
  const float* t2W    = (const float*)d_in[12];
  const float* t2b    = (const float*)d_in[13];
  const int*   src    = (const int*)d_in[14];
  const int*   dst    = (const int*)d_in[15];
  const int N = in_sizes[1];
  const int E = in_sizes[2];
  const int nLayers = in_sizes[8] / (HID*HID);
  float* out = (float*)d_out;

  char* w = (char*)d_ws;
  size_t off = 0;
  auto alloc = [&](size_t bytes)->void*{
    void* p = (void*)(w + off);
    off += (bytes + 255) & ~(size_t)255;
    return p;
  };
  float* hr      = (float*)alloc((size_t)N*HID*4);
  float* hi      = (float*)alloc((size_t)N*HID*4);
  float* zr      = (float*)alloc((size_t)N*HID*4);
  float* zi      = (float*)alloc((size_t)N*HID*4);
  int*   rowptr  = (int*)alloc((size_t)(N+1)*4);
  int*   cnt     = (int*)alloc((size_t)N*4);
  int*   nextpos = (int*)alloc((size_t)N*4);
  int*   srcS    = (int*)alloc((size_t)E*4);
  float* erS     = (float*)alloc((size_t)E*4);
  float* eiS     = (float*)alloc((size_t)E*4);
  int*   partials= (int*)alloc(1024);

  int nChunks = (N+255)/256;
  int eBlocks = (E+255)/256;
  int nTiles  = (N+TNODES-1)/TNODES;
  int aggBlocks = (N+3)/4;   // 4 waves (nodes) per 256-thread block

  k_zero<<<nChunks, 256, 0, stream>>>(cnt, N);
  k_hist<<<eBlocks, 256, 0, stream>>>(dst, cnt, E);
  k_scan1<<<nChunks, 256, 0, stream>>>(cnt, rowptr, partials, N);
  k_scan2<<<1, 256, 0, stream>>>(partials, nChunks);
  k_scan3<<<nChunks, 256, 0, stream>>>(rowptr, partials, nextpos, N, E);
  k_scatter<<<eBlocks, 256, 0, stream>>>(src, dst, d, w_real, w_imag,
                                         nextpos, srcS, erS, eiS, E);
  k_transform1<<<nTiles, 256, 0, stream>>>(h, t1rW, t1rb, t1iW, t1ib, hr, hi, N);
  for(int i=0;i<nLayers;i++){
    k_agg<<<aggBlocks, 256, 0, stream>>>(rowptr, srcS, erS, eiS, hr, hi, zr, zi, N);
    k_dense<<<nTiles, 256, 0, stream>>>(W1 + (size_t)i*HID*HID, b1 + (size_t)i*HID,
                                        W2 + (size_t)i*HID*HID, b2 + (size_t)i*HID,
                                        zr, zi, hr, hi, N);
  }
  k_final<<<(N+31)/32, 256, 0, stream>>>(hr, hi, t2W, t2b, out, N);
}

// Round 3
// 419.969 us; speedup vs baseline: 2.9899x; 1.0244x over previous
//
#include <hip/hip_runtime.h>
#include <math.h>

#define HID 64
#define IN_DIM 128
#define OUTC 8
#define TNODES 32   // nodes per block in dense kernels
#define PAD 68      // 64+4 floats, padded row stride for LDS

static __device__ __forceinline__ float dot4(float4 a, float4 b){
  return fmaf(a.x,b.x, fmaf(a.y,b.y, fmaf(a.z,b.z, a.w*b.w)));
}

__global__ void k_zero(int* __restrict__ p, int n){
  int i = blockIdx.x*blockDim.x + threadIdx.x;
  if(i<n) p[i]=0;
}

__global__ void k_hist(const int* __restrict__ dst, int* __restrict__ cnt, int E){
  int i = blockIdx.x*blockDim.x + threadIdx.x;
  if(i<E) atomicAdd(&cnt[dst[i]], 1);
}

// per-chunk exclusive scan of cnt -> rowptr(chunk-local), chunk sums -> partials
__global__ void k_scan1(const int* __restrict__ cnt, int* __restrict__ rowptr,
                        int* __restrict__ partials, int n){
  __shared__ int s[256];
  int tid = threadIdx.x; int gid = blockIdx.x*256 + tid;
  int v = (gid<n)? cnt[gid] : 0;
  s[tid] = v; __syncthreads();
  #pragma unroll
  for(int off=1; off<256; off<<=1){
    int t = (tid>=off)? s[tid-off] : 0; __syncthreads();
    s[tid] += t; __syncthreads();
  }
  if(gid<n) rowptr[gid] = s[tid] - v;       // exclusive within chunk
  if(tid==255) partials[blockIdx.x] = s[255];
}

__global__ void k_scan2(int* __restrict__ partials, int np){
  __shared__ int s[256];
  int tid = threadIdx.x;
  int v = (tid<np)? partials[tid] : 0;
  s[tid] = v; __syncthreads();
  #pragma unroll
  for(int off=1; off<256; off<<=1){
    int t = (tid>=off)? s[tid-off] : 0; __syncthreads();
    s[tid] += t; __syncthreads();
  }
  if(tid<np) partials[tid] = s[tid] - v;    // exclusive
}

__global__ void k_scan3(int* __restrict__ rowptr, const int* __restrict__ partials,
                        int* __restrict__ nextpos, int n, int E){
  int gid = blockIdx.x*256 + threadIdx.x;
  if(gid<n){
    int v = rowptr[gid] + partials[blockIdx.x];
    rowptr[gid] = v;
    nextpos[gid] = v;
  }
  if(gid==0) rowptr[n] = E;
}

// packed payload: e4S[p] = { bits(src), e_real, e_imag, 0 } — one 16B scattered
// store per edge instead of three 4B stores (cuts dirty-line amplification ~3x)
__global__ void k_scatter(const int* __restrict__ src, const int* __restrict__ dst,
                          const float* __restrict__ d, const float* __restrict__ wr,
                          const float* __restrict__ wi, int* __restrict__ nextpos,
                          float4* __restrict__ e4S, int E){
  int i = blockIdx.x*blockDim.x + threadIdx.x;
  if(i>=E) return;
  int s = src[i], t = dst[i];
  float dd = d[t]*d[s];
  int p = atomicAdd(&nextpos[t], 1);
  e4S[p] = make_float4(__int_as_float(s), dd*wr[i], dd*wi[i], 0.f);
}

// h[N,128] -> hrhi[(n*64+o)*2 + {0,1}] = relu(h @ W.T + b)  (interleaved r,i)
// 256 thr = 32 lanes (outputs o, o+32) x 8 groups x 4 nodes
__global__ __launch_bounds__(256) void k_transform1(
    const float* __restrict__ h, const float* __restrict__ Wr, const float* __restrict__ br,
    const float* __restrict__ Wi, const float* __restrict__ bi,
    float* __restrict__ hrhi, int N){
  __shared__ float sWr[64*PAD], sWi[64*PAD], sX[TNODES*PAD];
  int tid = threadIdx.x;
  int o = tid & 31, grp = tid >> 5;
  int node0 = blockIdx.x*TNODES;
  float accR[2][4], accI[2][4];
  #pragma unroll
  for(int q=0;q<2;q++)
    #pragma unroll
    for(int m=0;m<4;m++){ accR[q][m]=0.f; accI[q][m]=0.f; }
  for(int half=0; half<2; half++){
    if(half) __syncthreads();   // protect LDS reuse across halves
    #pragma unroll
    for(int t=0;t<4;t++){
      int f4 = tid + t*256; int o2 = f4>>4, kc = f4&15;
      *(float4*)&sWr[o2*PAD + kc*4] = *(const float4*)&Wr[o2*IN_DIM + half*64 + kc*4];
      *(float4*)&sWi[o2*PAD + kc*4] = *(const float4*)&Wi[o2*IN_DIM + half*64 + kc*4];
    }
    #pragma unroll
    for(int t=0;t<2;t++){
      int f4 = tid + t*256; int nl = f4>>4, kc = f4&15;
      int node = node0 + nl;
      float4 x = make_float4(0.f,0.f,0.f,0.f);
      if(node<N) x = *(const float4*)&h[node*IN_DIM + half*64 + kc*4];
      *(float4*)&sX[nl*PAD + kc*4] = x;
    }
    __syncthreads();
    #pragma unroll 4
    for(int jc=0;jc<16;jc++){
      float4 wra = *(const float4*)&sWr[o*PAD + jc*4];
      float4 wrb = *(const float4*)&sWr[(o+32)*PAD + jc*4];
      float4 wia = *(const float4*)&sWi[o*PAD + jc*4];
      float4 wib = *(const float4*)&sWi[(o+32)*PAD + jc*4];
      #pragma unroll
      for(int m=0;m<4;m++){
        float4 x = *(const float4*)&sX[(grp*4+m)*PAD + jc*4];
        accR[0][m] += dot4(x, wra);
        accR[1][m] += dot4(x, wrb);
        accI[0][m] += dot4(x, wia);
        accI[1][m] += dot4(x, wib);
      }
    }
  }
  float bra = br[o], brb = br[o+32], bia = bi[o], bib = bi[o+32];
  #pragma unroll
  for(int m=0;m<4;m++){
    int node = node0 + grp*4 + m;
    if(node<N){
      *(float2*)&hrhi[(node*HID+o)*2]    = make_float2(fmaxf(accR[0][m]+bra,0.f), fmaxf(accI[0][m]+bia,0.f));
      *(float2*)&hrhi[(node*HID+o+32)*2] = make_float2(fmaxf(accR[1][m]+brb,0.f), fmaxf(accI[1][m]+bib,0.f));
    }
  }
}

// CSR gather aggregation: one wave per dst node, lane = hidden dim.
// Payload: uniform float4 per edge; features: one b64 gather per edge per lane.
__global__ __launch_bounds__(256) void k_agg(
    const int* __restrict__ rowptr, const float4* __restrict__ e4S,
    const float* __restrict__ hrhi, float* __restrict__ zrzi, int N){
  int lane = threadIdx.x & 63;
  int node = (blockIdx.x*blockDim.x + threadIdx.x) >> 6;
  if(node>=N) return;
  int beg = rowptr[node], end = rowptr[node+1];
  float ar0=0.f, ai0=0.f, ar1=0.f, ai1=0.f;
  int j = beg;
  for(; j+2<=end; j+=2){
    float4 p0 = e4S[j], p1 = e4S[j+1];
    int s0 = __float_as_int(p0.x), s1 = __float_as_int(p1.x);
    float2 v0 = *(const float2*)&hrhi[(s0*HID+lane)*2];
    float2 v1 = *(const float2*)&hrhi[(s1*HID+lane)*2];
    ar0 = fmaf(p0.y, v0.x, ar0); ar0 = fmaf(-p0.z, v0.y, ar0);
    ai0 = fmaf(p0.z, v0.x, ai0); ai0 = fmaf( p0.y, v0.y, ai0);
    ar1 = fmaf(p1.y, v1.x, ar1); ar1 = fmaf(-p1.z, v1.y, ar1);
    ai1 = fmaf(p1.z, v1.x, ai1); ai1 = fmaf( p1.y, v1.y, ai1);
  }
  if(j<end){
    float4 p0 = e4S[j];
    int s0 = __float_as_int(p0.x);
    float2 v0 = *(const float2*)&hrhi[(s0*HID+lane)*2];
    ar0 = fmaf(p0.y, v0.x, ar0); ar0 = fmaf(-p0.z, v0.y, ar0);
    ai0 = fmaf(p0.z, v0.x, ai0); ai0 = fmaf( p0.y, v0.y, ai0);
  }
  *(float2*)&zrzi[(node*HID+lane)*2] = make_float2(ar0+ar1, ai0+ai1);
}

// fused complex dense layer, register-lean multi-pass version.
// 256 thr = 32 lanes (outputs o, o+32) x 8 groups x 4 nodes
__global__ __launch_bounds__(256) void k_dense(
    const float* __restrict__ W1, const float* __restrict__ b1,
    const float* __restrict__ W2, const float* __restrict__ b2,
    const float* __restrict__ zrzi, float* __restrict__ hrhi, int N){
  __shared__ float sW1[64*PAD], sW2[64*PAD], sZR[TNODES*PAD], sZI[TNODES*PAD];
  int tid = threadIdx.x;
  int o = tid & 31, grp = tid >> 5;
  int node0 = blockIdx.x*TNODES;
  #pragma unroll
  for(int t=0;t<4;t++){
    int f4 = tid + t*256; int o2 = f4>>4, kc = f4&15;
    *(float4*)&sW1[o2*PAD + kc*4] = *(const float4*)&W1[o2*HID + kc*4];
    *(float4*)&sW2[o2*PAD + kc*4] = *(const float4*)&W2[o2*HID + kc*4];
  }
  #pragma unroll
  for(int t=0;t<4;t++){
    int f4 = tid + t*256;         // 0..1023 over 32 nodes x 32 quads
    int nl = f4 >> 5, q = f4 & 31;
    int node = node0 + nl;
    float4 v = make_float4(0.f,0.f,0.f,0.f);
    if(node<N) v = *(const float4*)&zrzi[node*(2*HID) + q*4];
    sZR[nl*PAD + q*2]   = v.x;  sZI[nl*PAD + q*2]   = v.y;
    sZR[nl*PAD + q*2+1] = v.z;  sZI[nl*PAD + q*2+1] = v.w;
  }
  __syncthreads();

  // Pass A: accA = zr . W1^T
  float zrn[2][4];
  float accC[2][4];
  {
    float accA[2][4];
    #pragma unroll
    for(int q=0;q<2;q++)
      #pragma unroll
      for(int m=0;m<4;m++) accA[q][m]=0.f;
    #pragma unroll 4
    for(int jc=0;jc<16;jc++){
      float4 w1a = *(const float4*)&sW1[o*PAD + jc*4];
      float4 w1b = *(const float4*)&sW1[(o+32)*PAD + jc*4];
      #pragma unroll
      for(int m=0;m<4;m++){
        float4 xr = *(const float4*)&sZR[(grp*4+m)*PAD + jc*4];
        accA[0][m] += dot4(xr, w1a);
        accA[1][m] += dot4(xr, w1b);
      }
    }
    // Pass B/C: accB = zi . W2^T ; accC = zi . W1^T
    float accB[2][4];
    #pragma unroll
    for(int q=0;q<2;q++)
      #pragma unroll
      for(int m=0;m<4;m++){ accB[q][m]=0.f; accC[q][m]=0.f; }
    #pragma unroll 4
    for(int jc=0;jc<16;jc++){
      float4 w1a = *(const float4*)&sW1[o*PAD + jc*4];
      float4 w1b = *(const float4*)&sW1[(o+32)*PAD + jc*4];
      float4 w2a = *(const float4*)&sW2[o*PAD + jc*4];
      float4 w2b = *(const float4*)&sW2[(o+32)*PAD + jc*4];
      #pragma unroll
      for(int m=0;m<4;m++){
        float4 xi = *(const float4*)&sZI[(grp*4+m)*PAD + jc*4];
        accB[0][m] += dot4(xi, w2a);
        accB[1][m] += dot4(xi, w2b);
        accC[0][m] += dot4(xi, w1a);
        accC[1][m] += dot4(xi, w1b);
      }
    }
    float b1a = b1[o], b1b = b1[o+32], b2a = b2[o], b2b = b2[o+32];
    #pragma unroll
    for(int m=0;m<4;m++){
      zrn[0][m] = accA[0][m] + b1a - accB[0][m] - b2a;
      zrn[1][m] = accA[1][m] + b1b - accB[1][m] - b2b;
    }
  }
  __syncthreads();                 // all reads of sZR done
  #pragma unroll
  for(int m=0;m<4;m++){
    sZR[(grp*4+m)*PAD + o]      = zrn[0][m];   // pre-relu z_real_new tile
    sZR[(grp*4+m)*PAD + o + 32] = zrn[1][m];
  }
  __syncthreads();
  // Pass D: accD = zrn . W2^T
  float accD[2][4];
  #pragma unroll
  for(int q=0;q<2;q++)
    #pragma unroll
    for(int m=0;m<4;m++) accD[q][m]=0.f;
  #pragma unroll 4
  for(int jc=0;jc<16;jc++){
    float4 w2a = *(const float4*)&sW2[o*PAD + jc*4];
    float4 w2b = *(const float4*)&sW2[(o+32)*PAD + jc*4];
    #pragma unroll
    for(int m=0;m<4;m++){
      float4 x = *(const float4*)&sZR[(grp*4+m)*PAD + jc*4];
      accD[0][m] += dot4(x, w2a);
      accD[1][m] += dot4(x, w2b);
    }
  }
  float b1a = b1[o], b1b = b1[o+32], b2a = b2[o], b2b = b2[o+32];
  #pragma unroll
  for(int m=0;m<4;m++){
    int node = node0 + grp*4 + m;
    if(node<N){
      float zina = accD[0][m] + b2a + accC[0][m] + b1a;
      float zinb = accD[1][m] + b2b + accC[1][m] + b1b;
      *(float2*)&hrhi[(node*HID+o)*2]    = make_float2(fmaxf(zrn[0][m],0.f), fmaxf(zina,0.f));
      *(float2*)&hrhi[(node*HID+o+32)*2] = make_float2(fmaxf(zrn[1][m],0.f), fmaxf(zinb,0.f));
    }
  }
}

// logits (128->8) + log_softmax; 8 lanes per node; weights pre-permuted to
// match interleaved hrhi layout so the inner loop stays pure dot4.
__global__ __launch_bounds__(256) void k_final(
    const float* __restrict__ hrhi, const float* __restrict__ t2W,
    const float* __restrict__ t2b, float* __restrict__ out, int N){
  __shared__ float sW[OUTC*132], sWp[OUTC*132];
  int tid = threadIdx.x;
  {
    int o2 = tid>>5, kc = tid&31;   // 256 float4 = 8*128 floats exactly
    *(float4*)&sW[o2*132 + kc*4] = *(const float4*)&t2W[o2*128 + kc*4];
  }
  __syncthreads();
  if(tid < 128){
    int o2 = tid>>4, q = tid&15;
    int d0 = 2*q, d1 = 2*q+1;
    *(float4*)&sWp[o2*132 + q*4] = make_float4(
        sW[o2*132 + d0], sW[o2*132 + 64 + d0],
        sW[o2*132 + d1], sW[o2*132 + 64 + d1]);
  }
  __syncthreads();
  int o = tid&7, nl = tid>>3;
  int node = blockIdx.x*32 + nl;
  float acc = 0.f;
  if(node<N){
    acc = t2b[o];
    #pragma unroll
    for(int q=0;q<16;q++){
      float4 x = *(const float4*)&hrhi[node*(2*HID) + q*4];
      float4 w = *(const float4*)&sWp[o*132 + q*4];
      acc += dot4(x,w);
    }
  }
  float mx = acc;
  #pragma unroll
  for(int msk=4; msk>=1; msk>>=1) mx = fmaxf(mx, __shfl_xor(mx, msk, 8));
  float e = expf(acc - mx);
  float sm = e;
  #pragma unroll
  for(int msk=4; msk>=1; msk>>=1) sm += __shfl_xor(sm, msk, 8);
  if(node<N) out[node*OUTC+o] = (acc - mx) - logf(sm);
}

extern "C" void kernel_launch(void* const* d_in, const int* in_sizes, int n_in,
                              void* d_out, int out_size, void* d_ws, size_t ws_size,
                              hipStream_t stream) {
  const float* h      = (const float*)d_in[0];
  const float* d      = (const float*)d_in[1];
  const float* w_real = (const float*)d_in[2];
  const float* w_imag = (const float*)d_in[3];
  const float* t1rW   = (const float*)d_in[4];
  const float* t1rb   = (const float*)d_in[5];
  const float* t1iW   = (const float*)d_in[6];
  const float* t1ib   = (const float*)d_in[7];
  const float* W1     = (const float*)d_in[8];
  const float* b1     = (const float*)d_in[9];
  const float* W2     = (const float*)d_in[10];
  const float* b2     = (const float*)d_in[11];
  const float* t2W    = (const float*)d_in[12];
  const float* t2b    = (const float*)d_in[13];
  const int*   src    = (const int*)d_in[14];
  const int*   dst    = (const int*)d_in[15];
  const int N = in_sizes[1];
  const int E = in_sizes[2];
  const int nLayers = in_sizes[8] / (HID*HID);
  float* out = (float*)d_out;

  char* w = (char*)d_ws;
  size_t off = 0;
  auto alloc = [&](size_t bytes)->void*{
    void* p = (void*)(w + off);
    off += (bytes + 255) & ~(size_t)255;
    return p;
  };
  float*  hrhi    = (float*)alloc((size_t)N*2*HID*4);
  float*  zrzi    = (float*)alloc((size_t)N*2*HID*4);
  int*    rowptr  = (int*)alloc((size_t)(N+1)*4);
  int*    cnt     = (int*)alloc((size_t)N*4);
  int*    nextpos = (int*)alloc((size_t)N*4);
  float4* e4S     = (float4*)alloc((size_t)E*16);
  int*    partials= (int*)alloc(1024);

  int nChunks = (N+255)/256;
  int eBlocks = (E+255)/256;
  int nTiles  = (N+TNODES-1)/TNODES;
  int aggBlocks = (N+3)/4;   // 4 waves (nodes) per 256-thread block

  k_zero<<<nChunks, 256, 0, stream>>>(cnt, N);
  k_hist<<<eBlocks, 256, 0, stream>>>(dst, cnt, E);
  k_scan1<<<nChunks, 256, 0, stream>>>(cnt, rowptr, partials, N);
  k_scan2<<<1, 256, 0, stream>>>(partials, nChunks);
  k_scan3<<<nChunks, 256, 0, stream>>>(rowptr, partials, nextpos, N, E);
  k_scatter<<<eBlocks, 256, 0, stream>>>(src, dst, d, w_real, w_imag,
                                         nextpos, e4S, E);
  k_transform1<<<nTiles, 256, 0, stream>>>(h, t1rW, t1rb, t1iW, t1ib, hrhi, N);
  for(int i=0;i<nLayers;i++){
    k_agg<<<aggBlocks, 256, 0, stream>>>(rowptr, e4S, hrhi, zrzi, N);
    k_dense<<<nTiles, 256, 0, stream>>>(W1 + (size_t)i*HID*HID, b1 + (size_t)i*HID,
                                        W2 + (size_t)i*HID*HID, b2 + (size_t)i*HID,
                                        zrzi, hrhi, N);
  }
  k_final<<<(N+31)/32, 256, 0, stream>>>(hrhi, t2W, t2b, out, N);
}

// Round 4
// 405.871 us; speedup vs baseline: 3.0937x; 1.0347x over previous
//
#include <hip/hip_runtime.h>
#include <hip/hip_fp16.h>
#include <math.h>

#define HID 64
#define IN_DIM 128
#define OUTC 8
#define TN 64       // nodes per block in dense/transform kernels
#define PAD 68      // padded row stride (floats) for LDS

static __device__ __forceinline__ float dot4(float4 a, float4 b){
  return fmaf(a.x,b.x, fmaf(a.y,b.y, fmaf(a.z,b.z, a.w*b.w)));
}

__global__ void k_zero(int* __restrict__ p, int n){
  int i = blockIdx.x*blockDim.x + threadIdx.x;
  if(i<n) p[i]=0;
}

__global__ void k_hist(const int* __restrict__ dst, int* __restrict__ cnt, int E){
  int i = blockIdx.x*blockDim.x + threadIdx.x;
  if(i<E) atomicAdd(&cnt[dst[i]], 1);
}

// per-chunk exclusive scan of cnt -> rowptr(chunk-local), chunk sums -> partials
__global__ void k_scan1(const int* __restrict__ cnt, int* __restrict__ rowptr,
                        int* __restrict__ partials, int n){
  __shared__ int s[256];
  int tid = threadIdx.x; int gid = blockIdx.x*256 + tid;
  int v = (gid<n)? cnt[gid] : 0;
  s[tid] = v; __syncthreads();
  #pragma unroll
  for(int off=1; off<256; off<<=1){
    int t = (tid>=off)? s[tid-off] : 0; __syncthreads();
    s[tid] += t; __syncthreads();
  }
  if(gid<n) rowptr[gid] = s[tid] - v;       // exclusive within chunk
  if(tid==255) partials[blockIdx.x] = s[255];
}

__global__ void k_scan2(int* __restrict__ partials, int np){
  __shared__ int s[256];
  int tid = threadIdx.x;
  int v = (tid<np)? partials[tid] : 0;
  s[tid] = v; __syncthreads();
  #pragma unroll
  for(int off=1; off<256; off<<=1){
    int t = (tid>=off)? s[tid-off] : 0; __syncthreads();
    s[tid] += t; __syncthreads();
  }
  if(tid<np) partials[tid] = s[tid] - v;    // exclusive
}

__global__ void k_scan3(int* __restrict__ rowptr, const int* __restrict__ partials,
                        int* __restrict__ nextpos, int n, int E){
  int gid = blockIdx.x*256 + threadIdx.x;
  if(gid<n){
    int v = rowptr[gid] + partials[blockIdx.x];
    rowptr[gid] = v;
    nextpos[gid] = v;
  }
  if(gid==0) rowptr[n] = E;
}

// packed payload: e4S[p] = { bits(src), e_real, e_imag, 0 } — one 16B scattered
// store per edge
__global__ void k_scatter(const int* __restrict__ src, const int* __restrict__ dst,
                          const float* __restrict__ d, const float* __restrict__ wr,
                          const float* __restrict__ wi, int* __restrict__ nextpos,
                          float4* __restrict__ e4S, int E){
  int i = blockIdx.x*blockDim.x + threadIdx.x;
  if(i>=E) return;
  int s = src[i], t = dst[i];
  float dd = d[t]*d[s];
  int p = atomicAdd(&nextpos[t], 1);
  e4S[p] = make_float4(__int_as_float(s), dd*wr[i], dd*wi[i], 0.f);
}

// h[N,128] -> hrhi[node*64+o] = half2(relu(h@Wr.T+br), relu(h@Wi.T+bi))
// 256 thr = 16 o-lanes (outputs o,o+16,o+32,o+48) x 16 grps x 4 nodes; TN=64
__global__ __launch_bounds__(256) void k_transform1(
    const float* __restrict__ h, const float* __restrict__ Wr, const float* __restrict__ br,
    const float* __restrict__ Wi, const float* __restrict__ bi,
    __half2* __restrict__ hrhi, int N){
  __shared__ float sWr[64*PAD], sWi[64*PAD], sX[TN*PAD];
  int tid = threadIdx.x;
  int o = tid & 15, grp = tid >> 4;
  int node0 = blockIdx.x*TN;
  float accR[4][4], accI[4][4];
  #pragma unroll
  for(int r=0;r<4;r++)
    #pragma unroll
    for(int m=0;m<4;m++){ accR[r][m]=0.f; accI[r][m]=0.f; }
  for(int half=0; half<2; half++){
    if(half) __syncthreads();   // WAR on LDS reuse across halves
    #pragma unroll
    for(int t=0;t<4;t++){
      int f4 = tid + t*256; int row = f4>>4, kc = f4&15;
      *(float4*)&sWr[row*PAD + kc*4] = *(const float4*)&Wr[row*IN_DIM + half*64 + kc*4];
      *(float4*)&sWi[row*PAD + kc*4] = *(const float4*)&Wi[row*IN_DIM + half*64 + kc*4];
    }
    #pragma unroll
    for(int t=0;t<4;t++){
      int f4 = tid + t*256; int nl = f4>>4, kc = f4&15;
      int node = node0 + nl;
      float4 x = make_float4(0.f,0.f,0.f,0.f);
      if(node<N) x = *(const float4*)&h[node*IN_DIM + half*64 + kc*4];
      *(float4*)&sX[nl*PAD + kc*4] = x;
    }
    __syncthreads();
    #pragma unroll 2
    for(int jc=0;jc<16;jc++){
      float4 wr4[4], wi4[4];
      #pragma unroll
      for(int r=0;r<4;r++){
        wr4[r] = *(const float4*)&sWr[(o+16*r)*PAD + jc*4];
        wi4[r] = *(const float4*)&sWi[(o+16*r)*PAD + jc*4];
      }
      #pragma unroll
      for(int m=0;m<4;m++){
        float4 x = *(const float4*)&sX[(grp*4+m)*PAD + jc*4];
        #pragma unroll
        for(int r=0;r<4;r++){
          accR[r][m] += dot4(x, wr4[r]);
          accI[r][m] += dot4(x, wi4[r]);
        }
      }
    }
  }
  float brv[4], biv[4];
  #pragma unroll
  for(int r=0;r<4;r++){ brv[r]=br[o+16*r]; biv[r]=bi[o+16*r]; }
  #pragma unroll
  for(int m=0;m<4;m++){
    int node = node0 + grp*4 + m;
    if(node<N){
      #pragma unroll
      for(int r=0;r<4;r++){
        hrhi[node*HID + o + 16*r] =
          __floats2half2_rn(fmaxf(accR[r][m]+brv[r],0.f), fmaxf(accI[r][m]+biv[r],0.f));
      }
    }
  }
}

// CSR gather aggregation: one wave per dst node, lane = hidden dim.
// fp16 hrhi: 4B gather per edge per lane (half the fp32 traffic).
__global__ __launch_bounds__(256) void k_agg(
    const int* __restrict__ rowptr, const float4* __restrict__ e4S,
    const __half2* __restrict__ hrhi, float* __restrict__ zrzi, int N){
  int lane = threadIdx.x & 63;
  int node = (blockIdx.x*blockDim.x + threadIdx.x) >> 6;
  if(node>=N) return;
  int beg = rowptr[node], end = rowptr[node+1];
  float ar0=0.f, ai0=0.f, ar1=0.f, ai1=0.f;
  int j = beg;
  for(; j+2<=end; j+=2){
    float4 p0 = e4S[j], p1 = e4S[j+1];
    int s0 = __float_as_int(p0.x), s1 = __float_as_int(p1.x);
    float2 v0 = __half22float2(hrhi[s0*HID+lane]);
    float2 v1 = __half22float2(hrhi[s1*HID+lane]);
    ar0 = fmaf(p0.y, v0.x, ar0); ar0 = fmaf(-p0.z, v0.y, ar0);
    ai0 = fmaf(p0.z, v0.x, ai0); ai0 = fmaf( p0.y, v0.y, ai0);
    ar1 = fmaf(p1.y, v1.x, ar1); ar1 = fmaf(-p1.z, v1.y, ar1);
    ai1 = fmaf(p1.z, v1.x, ai1); ai1 = fmaf( p1.y, v1.y, ai1);
  }
  if(j<end){
    float4 p0 = e4S[j];
    int s0 = __float_as_int(p0.x);
    float2 v0 = __half22float2(hrhi[s0*HID+lane]);
    ar0 = fmaf(p0.y, v0.x, ar0); ar0 = fmaf(-p0.z, v0.y, ar0);
    ai0 = fmaf(p0.z, v0.x, ai0); ai0 = fmaf( p0.y, v0.y, ai0);
  }
  *(float2*)&zrzi[(node*HID+lane)*2] = make_float2(ar0+ar1, ai0+ai1);
}

// fused complex dense layer; merged A/B/C pass + 4o x 4m register blocking.
// 256 thr = 16 o-lanes x 16 grps x 4 nodes; TN=64
__global__ __launch_bounds__(256) void k_dense(
    const float* __restrict__ W1, const float* __restrict__ b1,
    const float* __restrict__ W2, const float* __restrict__ b2,
    const float* __restrict__ zrzi, __half2* __restrict__ hrhi, int N){
  __shared__ float sW1[64*PAD], sW2[64*PAD], sZR[TN*PAD], sZI[TN*PAD];
  int tid = threadIdx.x;
  int o = tid & 15, grp = tid >> 4;
  int node0 = blockIdx.x*TN;
  #pragma unroll
  for(int t=0;t<4;t++){
    int f4 = tid + t*256; int row = f4>>4, kc = f4&15;
    *(float4*)&sW1[row*PAD + kc*4] = *(const float4*)&W1[row*HID + kc*4];
    *(float4*)&sW2[row*PAD + kc*4] = *(const float4*)&W2[row*HID + kc*4];
  }
  #pragma unroll
  for(int t=0;t<8;t++){
    int f4 = tid + t*256;         // 0..2047 over 64 nodes x 32 quads
    int nl = f4 >> 5, q = f4 & 31;
    int node = node0 + nl;
    float4 v = make_float4(0.f,0.f,0.f,0.f);
    if(node<N) v = *(const float4*)&zrzi[node*(2*HID) + q*4];
    sZR[nl*PAD + q*2]   = v.x;  sZI[nl*PAD + q*2]   = v.y;
    sZR[nl*PAD + q*2+1] = v.z;  sZI[nl*PAD + q*2+1] = v.w;
  }
  __syncthreads();

  float b1v[4], b2v[4];
  #pragma unroll
  for(int r=0;r<4;r++){ b1v[r]=b1[o+16*r]; b2v[r]=b2[o+16*r]; }

  // merged pass A/B/C: accA = zr.W1, accB = zi.W2, accC = zi.W1
  float zrn[4][4], accC[4][4];
  {
    float accA[4][4], accB[4][4];
    #pragma unroll
    for(int r=0;r<4;r++)
      #pragma unroll
      for(int m=0;m<4;m++){ accA[r][m]=0.f; accB[r][m]=0.f; accC[r][m]=0.f; }
    #pragma unroll 2
    for(int jc=0;jc<16;jc++){
      float4 w1[4], w2[4];
      #pragma unroll
      for(int r=0;r<4;r++){
        w1[r] = *(const float4*)&sW1[(o+16*r)*PAD + jc*4];
        w2[r] = *(const float4*)&sW2[(o+16*r)*PAD + jc*4];
      }
      #pragma unroll
      for(int m=0;m<4;m++){
        float4 xr = *(const float4*)&sZR[(grp*4+m)*PAD + jc*4];
        float4 xi = *(const float4*)&sZI[(grp*4+m)*PAD + jc*4];
        #pragma unroll
        for(int r=0;r<4;r++){
          accA[r][m] += dot4(xr, w1[r]);
          accB[r][m] += dot4(xi, w2[r]);
          accC[r][m] += dot4(xi, w1[r]);
        }
      }
    }
    #pragma unroll
    for(int r=0;r<4;r++)
      #pragma unroll
      for(int m=0;m<4;m++)
        zrn[r][m] = accA[r][m] + b1v[r] - accB[r][m] - b2v[r];
  }
  __syncthreads();                 // all reads of sZR done
  #pragma unroll
  for(int m=0;m<4;m++)
    #pragma unroll
    for(int r=0;r<4;r++)
      sZR[(grp*4+m)*PAD + o + 16*r] = zrn[r][m];   // pre-relu z_real_new tile
  __syncthreads();
  // pass D: accD = zrn . W2
  float accD[4][4];
  #pragma unroll
  for(int r=0;r<4;r++)
    #pragma unroll
    for(int m=0;m<4;m++) accD[r][m]=0.f;
  #pragma unroll 2
  for(int jc=0;jc<16;jc++){
    float4 w2[4];
    #pragma unroll
    for(int r=0;r<4;r++)
      w2[r] = *(const float4*)&sW2[(o+16*r)*PAD + jc*4];
    #pragma unroll
    for(int m=0;m<4;m++){
      float4 x = *(const float4*)&sZR[(grp*4+m)*PAD + jc*4];
      #pragma unroll
      for(int r=0;r<4;r++)
        accD[r][m] += dot4(x, w2[r]);
    }
  }
  #pragma unroll
  for(int m=0;m<4;m++){
    int node = node0 + grp*4 + m;
    if(node<N){
      #pragma unroll
      for(int r=0;r<4;r++){
        float zin = accD[r][m] + b2v[r] + accC[r][m] + b1v[r];
        hrhi[node*HID + o + 16*r] =
          __floats2half2_rn(fmaxf(zrn[r][m],0.f), fmaxf(zin,0.f));
      }
    }
  }
}

// logits (128->8) + log_softmax; 8 lanes per node; weights permuted to match
// interleaved (r,i) hrhi layout.
__global__ __launch_bounds__(256) void k_final(
    const __half2* __restrict__ hrhi, const float* __restrict__ t2W,
    const float* __restrict__ t2b, float* __restrict__ out, int N){
  __shared__ float sW[OUTC*132];   // sW[o][2d]=t2W[o][d], sW[o][2d+1]=t2W[o][64+d]
  int tid = threadIdx.x;
  #pragma unroll
  for(int t=0;t<4;t++){
    int idx = tid + t*256;          // 0..1023
    int o2 = idx >> 7, j = idx & 127;
    int dd = j >> 1, part = j & 1;
    sW[o2*132 + j] = t2W[o2*128 + part*64 + dd];
  }
  __syncthreads();
  int o = tid&7, nl = tid>>3;
  int node = blockIdx.x*32 + nl;
  float acc = 0.f;
  if(node<N){
    acc = t2b[o];
    const uint4* hp = reinterpret_cast<const uint4*>(&hrhi[node*HID]);
    #pragma unroll
    for(int q=0;q<16;q++){
      uint4 v = hp[q];              // 4 half2 = dims 4q..4q+3
      __half2 h0 = *reinterpret_cast<__half2*>(&v.x);
      __half2 h1 = *reinterpret_cast<__half2*>(&v.y);
      __half2 h2 = *reinterpret_cast<__half2*>(&v.z);
      __half2 h3 = *reinterpret_cast<__half2*>(&v.w);
      float2 f0 = __half22float2(h0), f1 = __half22float2(h1);
      float2 f2 = __half22float2(h2), f3 = __half22float2(h3);
      float4 w0 = *(const float4*)&sW[o*132 + q*8];
      float4 w1 = *(const float4*)&sW[o*132 + q*8 + 4];
      acc += dot4(make_float4(f0.x,f0.y,f1.x,f1.y), w0);
      acc += dot4(make_float4(f2.x,f2.y,f3.x,f3.y), w1);
    }
  }
  float mx = acc;
  #pragma unroll
  for(int msk=4; msk>=1; msk>>=1) mx = fmaxf(mx, __shfl_xor(mx, msk, 8));
  float e = expf(acc - mx);
  float sm = e;
  #pragma unroll
  for(int msk=4; msk>=1; msk>>=1) sm += __shfl_xor(sm, msk, 8);
  if(node<N) out[node*OUTC+o] = (acc - mx) - logf(sm);
}

extern "C" void kernel_launch(void* const* d_in, const int* in_sizes, int n_in,
                              void* d_out, int out_size, void* d_ws, size_t ws_size,
                              hipStream_t stream) {
  const float* h      = (const float*)d_in[0];
  const float* d      = (const float*)d_in[1];
  const float* w_real = (const float*)d_in[2];
  const float* w_imag = (const float*)d_in[3];
  const float* t1rW   = (const float*)d_in[4];
  const float* t1rb   = (const float*)d_in[5];
  const float* t1iW   = (const float*)d_in[6];
  const float* t1ib   = (const float*)d_in[7];
  const float* W1     = (const float*)d_in[8];
  const float* b1     = (const float*)d_in[9];
  const float* W2     = (const float*)d_in[10];
  const float* b2     = (const float*)d_in[11];
  const float* t2W    = (const float*)d_in[12];
  const float* t2b    = (const float*)d_in[13];
  const int*   src    = (const int*)d_in[14];
  const int*   dst    = (const int*)d_in[15];
  const int N = in_sizes[1];
  const int E = in_sizes[2];
  const int nLayers = in_sizes[8] / (HID*HID);
  float* out = (float*)d_out;

  char* w = (char*)d_ws;
  size_t off = 0;
  auto alloc = [&](size_t bytes)->void*{
    void* p = (void*)(w + off);
    off += (bytes + 255) & ~(size_t)255;
    return p;
  };
  __half2* hrhi   = (__half2*)alloc((size_t)N*HID*sizeof(__half2));
  float*  zrzi    = (float*)alloc((size_t)N*2*HID*4);
  int*    rowptr  = (int*)alloc((size_t)(N+1)*4);
  int*    cnt     = (int*)alloc((size_t)N*4);
  int*    nextpos = (int*)alloc((size_t)N*4);
  float4* e4S     = (float4*)alloc((size_t)E*16);
  int*    partials= (int*)alloc(1024);

  int nChunks = (N+255)/256;
  int eBlocks = (E+255)/256;
  int nTiles  = (N+TN-1)/TN;
  int aggBlocks = (N+3)/4;   // 4 waves (nodes) per 256-thread block

  k_zero<<<nChunks, 256, 0, stream>>>(cnt, N);
  k_hist<<<eBlocks, 256, 0, stream>>>(dst, cnt, E);
  k_scan1<<<nChunks, 256, 0, stream>>>(cnt, rowptr, partials, N);
  k_scan2<<<1, 256, 0, stream>>>(partials, nChunks);
  k_scan3<<<nChunks, 256, 0, stream>>>(rowptr, partials, nextpos, N, E);
  k_scatter<<<eBlocks, 256, 0, stream>>>(src, dst, d, w_real, w_imag,
                                         nextpos, e4S, E);
  k_transform1<<<nTiles, 256, 0, stream>>>(h, t1rW, t1rb, t1iW, t1ib, hrhi, N);
  for(int i=0;i<nLayers;i++){
    k_agg<<<aggBlocks, 256, 0, stream>>>(rowptr, e4S, hrhi, zrzi, N);
    k_dense<<<nTiles, 256, 0, stream>>>(W1 + (size_t)i*HID*HID, b1 + (size_t)i*HID,
                                        W2 + (size_t)i*HID*HID, b2 + (size_t)i*HID,
                                        zrzi, hrhi, N);
  }
  k_final<<<(N+31)/32, 256, 0, stream>>>(hrhi, t2W, t2b, out, N);
}

// Round 5
// 379.863 us; speedup vs baseline: 3.3056x; 1.0685x over previous
//
#include <hip/hip_runtime.h>
#include <hip/hip_fp16.h>
#include <math.h>

#define HID 64
#define IN_DIM 128
#define OUTC 8
#define TN 64       // nodes per block in dense/transform kernels
#define PAD 68      // padded row stride (floats) for LDS

static __device__ __forceinline__ float dot4(float4 a, float4 b){
  return fmaf(a.x,b.x, fmaf(a.y,b.y, fmaf(a.z,b.z, a.w*b.w)));
}

__global__ void k_zero(int* __restrict__ p, int n){
  int i = blockIdx.x*blockDim.x + threadIdx.x;
  if(i<n) p[i]=0;
}

// hist also records each edge's rank among same-dst edges (return of atomicAdd)
__global__ void k_hist(const int* __restrict__ dst, int* __restrict__ cnt,
                       int* __restrict__ rank, int E){
  int i = blockIdx.x*blockDim.x + threadIdx.x;
  if(i<E) rank[i] = atomicAdd(&cnt[dst[i]], 1);
}

// per-chunk exclusive scan of cnt -> rowptr(chunk-local), chunk sums -> partials
__global__ void k_scan1(const int* __restrict__ cnt, int* __restrict__ rowptr,
                        int* __restrict__ partials, int n){
  __shared__ int s[256];
  int tid = threadIdx.x; int gid = blockIdx.x*256 + tid;
  int v = (gid<n)? cnt[gid] : 0;
  s[tid] = v; __syncthreads();
  #pragma unroll
  for(int off=1; off<256; off<<=1){
    int t = (tid>=off)? s[tid-off] : 0; __syncthreads();
    s[tid] += t; __syncthreads();
  }
  if(gid<n) rowptr[gid] = s[tid] - v;       // exclusive within chunk
  if(tid==255) partials[blockIdx.x] = s[255];
}

__global__ void k_scan2(int* __restrict__ partials, int np){
  __shared__ int s[256];
  int tid = threadIdx.x;
  int v = (tid<np)? partials[tid] : 0;
  s[tid] = v; __syncthreads();
  #pragma unroll
  for(int off=1; off<256; off<<=1){
    int t = (tid>=off)? s[tid-off] : 0; __syncthreads();
    s[tid] += t; __syncthreads();
  }
  if(tid<np) partials[tid] = s[tid] - v;    // exclusive
}

__global__ void k_scan3(int* __restrict__ rowptr, const int* __restrict__ partials,
                        int n, int E){
  int gid = blockIdx.x*256 + threadIdx.x;
  if(gid<n) rowptr[gid] += partials[blockIdx.x];
  if(gid==0) rowptr[n] = E;
}

// packed payload: e4S[p] = { bits(src), e_real, e_imag, 0 }; position is
// rowptr[dst] + rank  (NO atomics here — rank captured in k_hist)
__global__ void k_scatter(const int* __restrict__ src, const int* __restrict__ dst,
                          const float* __restrict__ d, const float* __restrict__ wr,
                          const float* __restrict__ wi,
                          const int* __restrict__ rowptr, const int* __restrict__ rank,
                          float4* __restrict__ e4S, int E){
  int i = blockIdx.x*blockDim.x + threadIdx.x;
  if(i>=E) return;
  int s = src[i], t = dst[i];
  float dd = d[t]*d[s];
  int p = rowptr[t] + rank[i];
  e4S[p] = make_float4(__int_as_float(s), dd*wr[i], dd*wi[i], 0.f);
}

// h[N,128] -> hrhi[node*64+o] = half2(relu(h@Wr.T+br), relu(h@Wi.T+bi))
// 256 thr = 16 o-lanes (outputs o,o+16,o+32,o+48) x 16 grps x 4 nodes; TN=64
__global__ __launch_bounds__(256) void k_transform1(
    const float* __restrict__ h, const float* __restrict__ Wr, const float* __restrict__ br,
    const float* __restrict__ Wi, const float* __restrict__ bi,
    __half2* __restrict__ hrhi, int N){
  __shared__ float sWr[64*PAD], sWi[64*PAD], sX[TN*PAD];
  int tid = threadIdx.x;
  int o = tid & 15, grp = tid >> 4;
  int node0 = blockIdx.x*TN;
  float accR[4][4], accI[4][4];
  #pragma unroll
  for(int r=0;r<4;r++)
    #pragma unroll
    for(int m=0;m<4;m++){ accR[r][m]=0.f; accI[r][m]=0.f; }
  for(int half=0; half<2; half++){
    if(half) __syncthreads();   // WAR on LDS reuse across halves
    #pragma unroll
    for(int t=0;t<4;t++){
      int f4 = tid + t*256; int row = f4>>4, kc = f4&15;
      *(float4*)&sWr[row*PAD + kc*4] = *(const float4*)&Wr[row*IN_DIM + half*64 + kc*4];
      *(float4*)&sWi[row*PAD + kc*4] = *(const float4*)&Wi[row*IN_DIM + half*64 + kc*4];
    }
    #pragma unroll
    for(int t=0;t<4;t++){
      int f4 = tid + t*256; int nl = f4>>4, kc = f4&15;
      int node = node0 + nl;
      float4 x = make_float4(0.f,0.f,0.f,0.f);
      if(node<N) x = *(const float4*)&h[node*IN_DIM + half*64 + kc*4];
      *(float4*)&sX[nl*PAD + kc*4] = x;
    }
    __syncthreads();
    #pragma unroll 2
    for(int jc=0;jc<16;jc++){
      float4 wr4[4], wi4[4];
      #pragma unroll
      for(int r=0;r<4;r++){
        wr4[r] = *(const float4*)&sWr[(o+16*r)*PAD + jc*4];
        wi4[r] = *(const float4*)&sWi[(o+16*r)*PAD + jc*4];
      }
      #pragma unroll
      for(int m=0;m<4;m++){
        float4 x = *(const float4*)&sX[(grp*4+m)*PAD + jc*4];
        #pragma unroll
        for(int r=0;r<4;r++){
          accR[r][m] += dot4(x, wr4[r]);
          accI[r][m] += dot4(x, wi4[r]);
        }
      }
    }
  }
  float brv[4], biv[4];
  #pragma unroll
  for(int r=0;r<4;r++){ brv[r]=br[o+16*r]; biv[r]=bi[o+16*r]; }
  #pragma unroll
  for(int m=0;m<4;m++){
    int node = node0 + grp*4 + m;
    if(node<N){
      #pragma unroll
      for(int r=0;r<4;r++){
        hrhi[node*HID + o + 16*r] =
          __floats2half2_rn(fmaxf(accR[r][m]+brv[r],0.f), fmaxf(accI[r][m]+biv[r],0.f));
      }
    }
  }
}

// CSR gather aggregation, 4 nodes per wave (contiguous edge range), flat
// unroll-4 over the range -> 4 payload loads + 4 gathers in flight.
// Accumulator selected by wave-uniform if-chain on row boundaries.
__global__ __launch_bounds__(256) void k_agg(
    const int* __restrict__ rowptr, const float4* __restrict__ e4S,
    const __half2* __restrict__ hrhi, float* __restrict__ zrzi, int N){
  int lane = threadIdx.x & 63;
  int wid = blockIdx.x*(blockDim.x>>6) + (threadIdx.x>>6);
  int n0 = wid*4;
  if(n0>=N) return;
  int r0 = rowptr[n0];
  int r1 = rowptr[min(n0+1,N)];
  int r2 = rowptr[min(n0+2,N)];
  int r3 = rowptr[min(n0+3,N)];
  int r4 = rowptr[min(n0+4,N)];
  float ar0=0.f,ai0=0.f, ar1=0.f,ai1=0.f, ar2=0.f,ai2=0.f, ar3=0.f,ai3=0.f;

#define ACC(J,P,V)                                               \
  if((J)<r1){ ar0=fmaf(P.y,V.x,ar0); ar0=fmaf(-P.z,V.y,ar0);     \
              ai0=fmaf(P.z,V.x,ai0); ai0=fmaf( P.y,V.y,ai0); }   \
  else if((J)<r2){ ar1=fmaf(P.y,V.x,ar1); ar1=fmaf(-P.z,V.y,ar1);\
              ai1=fmaf(P.z,V.x,ai1); ai1=fmaf( P.y,V.y,ai1); }   \
  else if((J)<r3){ ar2=fmaf(P.y,V.x,ar2); ar2=fmaf(-P.z,V.y,ar2);\
              ai2=fmaf(P.z,V.x,ai2); ai2=fmaf( P.y,V.y,ai2); }   \
  else      { ar3=fmaf(P.y,V.x,ar3); ar3=fmaf(-P.z,V.y,ar3);     \
              ai3=fmaf(P.z,V.x,ai3); ai3=fmaf( P.y,V.y,ai3); }

  for(int jb=r0; jb<r4; jb+=4){
    int j1c = min(jb+1, r4-1);
    int j2c = min(jb+2, r4-1);
    int j3c = min(jb+3, r4-1);
    float4 p0 = e4S[jb],  p1 = e4S[j1c];
    float4 p2 = e4S[j2c], p3 = e4S[j3c];
    float2 v0 = __half22float2(hrhi[__float_as_int(p0.x)*HID + lane]);
    float2 v1 = __half22float2(hrhi[__float_as_int(p1.x)*HID + lane]);
    float2 v2 = __half22float2(hrhi[__float_as_int(p2.x)*HID + lane]);
    float2 v3 = __half22float2(hrhi[__float_as_int(p3.x)*HID + lane]);
    ACC(jb, p0, v0);
    if(jb+1<r4){ ACC(jb+1, p1, v1); }
    if(jb+2<r4){ ACC(jb+2, p2, v2); }
    if(jb+3<r4){ ACC(jb+3, p3, v3); }
  }
#undef ACC

  if(n0+0<N) *(float2*)&zrzi[((n0+0)*HID+lane)*2] = make_float2(ar0, ai0);
  if(n0+1<N) *(float2*)&zrzi[((n0+1)*HID+lane)*2] = make_float2(ar1, ai1);
  if(n0+2<N) *(float2*)&zrzi[((n0+2)*HID+lane)*2] = make_float2(ar2, ai2);
  if(n0+3<N) *(float2*)&zrzi[((n0+3)*HID+lane)*2] = make_float2(ar3, ai3);
}

// fused complex dense layer; merged A/B/C pass + 4o x 4m register blocking.
// 256 thr = 16 o-lanes x 16 grps x 4 nodes; TN=64
__global__ __launch_bounds__(256) void k_dense(
    const float* __restrict__ W1, const float* __restrict__ b1,
    const float* __restrict__ W2, const float* __restrict__ b2,
    const float* __restrict__ zrzi, __half2* __restrict__ hrhi, int N){
  __shared__ float sW1[64*PAD], sW2[64*PAD], sZR[TN*PAD], sZI[TN*PAD];
  int tid = threadIdx.x;
  int o = tid & 15, grp = tid >> 4;
  int node0 = blockIdx.x*TN;
  #pragma unroll
  for(int t=0;t<4;t++){
    int f4 = tid + t*256; int row = f4>>4, kc = f4&15;
    *(float4*)&sW1[row*PAD + kc*4] = *(const float4*)&W1[row*HID + kc*4];
    *(float4*)&sW2[row*PAD + kc*4] = *(const float4*)&W2[row*HID + kc*4];
  }
  #pragma unroll
  for(int t=0;t<8;t++){
    int f4 = tid + t*256;         // 0..2047 over 64 nodes x 32 quads
    int nl = f4 >> 5, q = f4 & 31;
    int node = node0 + nl;
    float4 v = make_float4(0.f,0.f,0.f,0.f);
    if(node<N) v = *(const float4*)&zrzi[node*(2*HID) + q*4];
    sZR[nl*PAD + q*2]   = v.x;  sZI[nl*PAD + q*2]   = v.y;
    sZR[nl*PAD + q*2+1] = v.z;  sZI[nl*PAD + q*2+1] = v.w;
  }
  __syncthreads();

  float b1v[4], b2v[4];
  #pragma unroll
  for(int r=0;r<4;r++){ b1v[r]=b1[o+16*r]; b2v[r]=b2[o+16*r]; }

  // merged pass A/B/C: accA = zr.W1, accB = zi.W2, accC = zi.W1
  float zrn[4][4], accC[4][4];
  {
    float accA[4][4], accB[4][4];
    #pragma unroll
    for(int r=0;r<4;r++)
      #pragma unroll
      for(int m=0;m<4;m++){ accA[r][m]=0.f; accB[r][m]=0.f; accC[r][m]=0.f; }
    #pragma unroll 2
    for(int jc=0;jc<16;jc++){
      float4 w1[4], w2[4];
      #pragma unroll
      for(int r=0;r<4;r++){
        w1[r] = *(const float4*)&sW1[(o+16*r)*PAD + jc*4];
        w2[r] = *(const float4*)&sW2[(o+16*r)*PAD + jc*4];
      }
      #pragma unroll
      for(int m=0;m<4;m++){
        float4 xr = *(const float4*)&sZR[(grp*4+m)*PAD + jc*4];
        float4 xi = *(const float4*)&sZI[(grp*4+m)*PAD + jc*4];
        #pragma unroll
        for(int r=0;r<4;r++){
          accA[r][m] += dot4(xr, w1[r]);
          accB[r][m] += dot4(xi, w2[r]);
          accC[r][m] += dot4(xi, w1[r]);
        }
      }
    }
    #pragma unroll
    for(int r=0;r<4;r++)
      #pragma unroll
      for(int m=0;m<4;m++)
        zrn[r][m] = accA[r][m] + b1v[r] - accB[r][m] - b2v[r];
  }
  __syncthreads();                 // all reads of sZR done
  #pragma unroll
  for(int m=0;m<4;m++)
    #pragma unroll
    for(int r=0;r<4;r++)
      sZR[(grp*4+m)*PAD + o + 16*r] = zrn[r][m];   // pre-relu z_real_new tile
  __syncthreads();
  // pass D: accD = zrn . W2
  float accD[4][4];
  #pragma unroll
  for(int r=0;r<4;r++)
    #pragma unroll
    for(int m=0;m<4;m++) accD[r][m]=0.f;
  #pragma unroll 2
  for(int jc=0;jc<16;jc++){
    float4 w2[4];
    #pragma unroll
    for(int r=0;r<4;r++)
      w2[r] = *(const float4*)&sW2[(o+16*r)*PAD + jc*4];
    #pragma unroll
    for(int m=0;m<4;m++){
      float4 x = *(const float4*)&sZR[(grp*4+m)*PAD + jc*4];
      #pragma unroll
      for(int r=0;r<4;r++)
        accD[r][m] += dot4(x, w2[r]);
    }
  }
  #pragma unroll
  for(int m=0;m<4;m++){
    int node = node0 + grp*4 + m;
    if(node<N){
      #pragma unroll
      for(int r=0;r<4;r++){
        float zin = accD[r][m] + b2v[r] + accC[r][m] + b1v[r];
        hrhi[node*HID + o + 16*r] =
          __floats2half2_rn(fmaxf(zrn[r][m],0.f), fmaxf(zin,0.f));
      }
    }
  }
}

// logits (128->8) + log_softmax; 8 lanes per node; weights permuted to match
// interleaved (r,i) hrhi layout.
__global__ __launch_bounds__(256) void k_final(
    const __half2* __restrict__ hrhi, const float* __restrict__ t2W,
    const float* __restrict__ t2b, float* __restrict__ out, int N){
  __shared__ float sW[OUTC*132];   // sW[o][2d]=t2W[o][d], sW[o][2d+1]=t2W[o][64+d]
  int tid = threadIdx.x;
  #pragma unroll
  for(int t=0;t<4;t++){
    int idx = tid + t*256;          // 0..1023
    int o2 = idx >> 7, j = idx & 127;
    int dd = j >> 1, part = j & 1;
    sW[o2*132 + j] = t2W[o2*128 + part*64 + dd];
  }
  __syncthreads();
  int o = tid&7, nl = tid>>3;
  int node = blockIdx.x*32 + nl;
  float acc = 0.f;
  if(node<N){
    acc = t2b[o];
    const uint4* hp = reinterpret_cast<const uint4*>(&hrhi[node*HID]);
    #pragma unroll
    for(int q=0;q<16;q++){
      uint4 v = hp[q];              // 4 half2 = dims 4q..4q+3
      __half2 h0 = *reinterpret_cast<__half2*>(&v.x);
      __half2 h1 = *reinterpret_cast<__half2*>(&v.y);
      __half2 h2 = *reinterpret_cast<__half2*>(&v.z);
      __half2 h3 = *reinterpret_cast<__half2*>(&v.w);
      float2 f0 = __half22float2(h0), f1 = __half22float2(h1);
      float2 f2 = __half22float2(h2), f3 = __half22float2(h3);
      float4 w0 = *(const float4*)&sW[o*132 + q*8];
      float4 w1 = *(const float4*)&sW[o*132 + q*8 + 4];
      acc += dot4(make_float4(f0.x,f0.y,f1.x,f1.y), w0);
      acc += dot4(make_float4(f2.x,f2.y,f3.x,f3.y), w1);
    }
  }
  float mx = acc;
  #pragma unroll
  for(int msk=4; msk>=1; msk>>=1) mx = fmaxf(mx, __shfl_xor(mx, msk, 8));
  float e = expf(acc - mx);
  float sm = e;
  #pragma unroll
  for(int msk=4; msk>=1; msk>>=1) sm += __shfl_xor(sm, msk, 8);
  if(node<N) out[node*OUTC+o] = (acc - mx) - logf(sm);
}

extern "C" void kernel_launch(void* const* d_in, const int* in_sizes, int n_in,
                              void* d_out, int out_size, void* d_ws, size_t ws_size,
                              hipStream_t stream) {
  const float* h      = (const float*)d_in[0];
  const float* d      = (const float*)d_in[1];
  const float* w_real = (const float*)d_in[2];
  const float* w_imag = (const float*)d_in[3];
  const float* t1rW   = (const float*)d_in[4];
  const float* t1rb   = (const float*)d_in[5];
  const float* t1iW   = (const float*)d_in[6];
  const float* t1ib   = (const float*)d_in[7];
  const float* W1     = (const float*)d_in[8];
  const float* b1     = (const float*)d_in[9];
  const float* W2     = (const float*)d_in[10];
  const float* b2     = (const float*)d_in[11];
  const float* t2W    = (const float*)d_in[12];
  const float* t2b    = (const float*)d_in[13];
  const int*   src    = (const int*)d_in[14];
  const int*   dst    = (const int*)d_in[15];
  const int N = in_sizes[1];
  const int E = in_sizes[2];
  const int nLayers = in_sizes[8] / (HID*HID);
  float* out = (float*)d_out;

  char* w = (char*)d_ws;
  size_t off = 0;
  auto alloc = [&](size_t bytes)->void*{
    void* p = (void*)(w + off);
    off += (bytes + 255) & ~(size_t)255;
    return p;
  };
  __half2* hrhi   = (__half2*)alloc((size_t)N*HID*sizeof(__half2));
  float*  zrzi    = (float*)alloc((size_t)N*2*HID*4);
  int*    rowptr  = (int*)alloc((size_t)(N+1)*4);
  int*    cnt     = (int*)alloc((size_t)N*4);
  int*    rank    = (int*)alloc((size_t)E*4);
  float4* e4S     = (float4*)alloc((size_t)E*16);
  int*    partials= (int*)alloc(1024);

  int nChunks = (N+255)/256;
  int eBlocks = (E+255)/256;
  int nTiles  = (N+TN-1)/TN;
  int aggWaves  = (N+3)/4;                 // 4 nodes per wave
  int aggBlocks = (aggWaves+3)/4;          // 4 waves per 256-thread block

  k_zero<<<nChunks, 256, 0, stream>>>(cnt, N);
  k_hist<<<eBlocks, 256, 0, stream>>>(dst, cnt, rank, E);
  k_scan1<<<nChunks, 256, 0, stream>>>(cnt, rowptr, partials, N);
  k_scan2<<<1, 256, 0, stream>>>(partials, nChunks);
  k_scan3<<<nChunks, 256, 0, stream>>>(rowptr, partials, N, E);
  k_scatter<<<eBlocks, 256, 0, stream>>>(src, dst, d, w_real, w_imag,
                                         rowptr, rank, e4S, E);
  k_transform1<<<nTiles, 256, 0, stream>>>(h, t1rW, t1rb, t1iW, t1ib, hrhi, N);
  for(int i=0;i<nLayers;i++){
    k_agg<<<aggBlocks, 256, 0, stream>>>(rowptr, e4S, hrhi, zrzi, N);
    k_dense<<<nTiles, 256, 0, stream>>>(W1 + (size_t)i*HID*HID, b1 + (size_t)i*HID,
                                        W2 + (size_t)i*HID*HID, b2 + (size_t)i*HID,
                                        zrzi, hrhi, N);
  }
  k_final<<<(N+31)/32, 256, 0, stream>>>(hrhi, t2W, t2b, out, N);
}

// Round 6
// 368.997 us; speedup vs baseline: 3.4029x; 1.0294x over previous
//
#include <hip/hip_runtime.h>
#include <hip/hip_fp16.h>
#include <math.h>

#define HID 64
#define IN_DIM 128
#define OUTC 8
#define TN 64       // nodes per block in dense/transform kernels
#define PAD 68      // padded row stride (floats) for LDS

static __device__ __forceinline__ float dot4(float4 a, float4 b){
  return fmaf(a.x,b.x, fmaf(a.y,b.y, fmaf(a.z,b.z, a.w*b.w)));
}

__global__ void k_zero(int* __restrict__ p, int n){
  int i = blockIdx.x*blockDim.x + threadIdx.x;
  if(i<n) p[i]=0;
}

// hist also records each edge's rank among same-dst edges (return of atomicAdd)
__global__ void k_hist(const int* __restrict__ dst, int* __restrict__ cnt,
                       int* __restrict__ rank, int E){
  int i = blockIdx.x*blockDim.x + threadIdx.x;
  if(i<E) rank[i] = atomicAdd(&cnt[dst[i]], 1);
}

// per-chunk exclusive scan of PADDED counts -> rowptr(chunk-local), chunk sums
__global__ void k_scan1(const int* __restrict__ cnt, int* __restrict__ rowptr,
                        int* __restrict__ partials, int n){
  __shared__ int s[256];
  int tid = threadIdx.x; int gid = blockIdx.x*256 + tid;
  int v = (gid<n)? ((cnt[gid]+3)&~3) : 0;   // pad each row to multiple of 4
  s[tid] = v; __syncthreads();
  #pragma unroll
  for(int off=1; off<256; off<<=1){
    int t = (tid>=off)? s[tid-off] : 0; __syncthreads();
    s[tid] += t; __syncthreads();
  }
  if(gid<n) rowptr[gid] = s[tid] - v;       // exclusive within chunk
  if(tid==255) partials[blockIdx.x] = s[255];
}

__global__ void k_scan2(int* __restrict__ partials, int* __restrict__ total, int np){
  __shared__ int s[256];
  int tid = threadIdx.x;
  int v = (tid<np)? partials[tid] : 0;
  s[tid] = v; __syncthreads();
  #pragma unroll
  for(int off=1; off<256; off<<=1){
    int t = (tid>=off)? s[tid-off] : 0; __syncthreads();
    s[tid] += t; __syncthreads();
  }
  if(tid==np-1) *total = s[tid];            // padded edge total
  if(tid<np) partials[tid] = s[tid] - v;    // exclusive
}

__global__ void k_scan3(int* __restrict__ rowptr, const int* __restrict__ partials,
                        const int* __restrict__ total, int n){
  int gid = blockIdx.x*256 + threadIdx.x;
  if(gid<n) rowptr[gid] += partials[blockIdx.x];
  if(gid==0) rowptr[n] = *total;
}

// zero-fill the <=3 pad slots per node (dummy edges: src=0, er=ei=0)
__global__ void k_fillpad(const int* __restrict__ cnt, const int* __restrict__ rowptr,
                          float4* __restrict__ e4S, int N){
  int n = blockIdx.x*blockDim.x + threadIdx.x;
  if(n>=N) return;
  int p = rowptr[n] + cnt[n], e = rowptr[n+1];
  for(; p<e; ++p) e4S[p] = make_float4(0.f,0.f,0.f,0.f);
}

// packed payload: e4S[p] = { bits(src), e_real, e_imag, 0 }; position is
// rowptr[dst] + rank  (NO atomics here — rank captured in k_hist)
__global__ void k_scatter(const int* __restrict__ src, const int* __restrict__ dst,
                          const float* __restrict__ d, const float* __restrict__ wr,
                          const float* __restrict__ wi,
                          const int* __restrict__ rowptr, const int* __restrict__ rank,
                          float4* __restrict__ e4S, int E){
  int i = blockIdx.x*blockDim.x + threadIdx.x;
  if(i>=E) return;
  int s = src[i], t = dst[i];
  float dd = d[t]*d[s];
  int p = rowptr[t] + rank[i];
  e4S[p] = make_float4(__int_as_float(s), dd*wr[i], dd*wi[i], 0.f);
}

// h[N,128] -> hrhi[node*64+o] = half2(relu(h@Wr.T+br), relu(h@Wi.T+bi))
// 256 thr = 16 o-lanes (outputs o,o+16,o+32,o+48) x 16 grps x 4 nodes; TN=64
__global__ __launch_bounds__(256) void k_transform1(
    const float* __restrict__ h, const float* __restrict__ Wr, const float* __restrict__ br,
    const float* __restrict__ Wi, const float* __restrict__ bi,
    __half2* __restrict__ hrhi, int N){
  __shared__ float sWr[64*PAD], sWi[64*PAD], sX[TN*PAD];
  int tid = threadIdx.x;
  int o = tid & 15, grp = tid >> 4;
  int node0 = blockIdx.x*TN;
  float accR[4][4], accI[4][4];
  #pragma unroll
  for(int r=0;r<4;r++)
    #pragma unroll
    for(int m=0;m<4;m++){ accR[r][m]=0.f; accI[r][m]=0.f; }
  for(int half=0; half<2; half++){
    if(half) __syncthreads();   // WAR on LDS reuse across halves
    #pragma unroll
    for(int t=0;t<4;t++){
      int f4 = tid + t*256; int row = f4>>4, kc = f4&15;
      *(float4*)&sWr[row*PAD + kc*4] = *(const float4*)&Wr[row*IN_DIM + half*64 + kc*4];
      *(float4*)&sWi[row*PAD + kc*4] = *(const float4*)&Wi[row*IN_DIM + half*64 + kc*4];
    }
    #pragma unroll
    for(int t=0;t<4;t++){
      int f4 = tid + t*256; int nl = f4>>4, kc = f4&15;
      int node = node0 + nl;
      float4 x = make_float4(0.f,0.f,0.f,0.f);
      if(node<N) x = *(const float4*)&h[node*IN_DIM + half*64 + kc*4];
      *(float4*)&sX[nl*PAD + kc*4] = x;
    }
    __syncthreads();
    #pragma unroll 2
    for(int jc=0;jc<16;jc++){
      float4 wr4[4], wi4[4];
      #pragma unroll
      for(int r=0;r<4;r++){
        wr4[r] = *(const float4*)&sWr[(o+16*r)*PAD + jc*4];
        wi4[r] = *(const float4*)&sWi[(o+16*r)*PAD + jc*4];
      }
      #pragma unroll
      for(int m=0;m<4;m++){
        float4 x = *(const float4*)&sX[(grp*4+m)*PAD + jc*4];
        #pragma unroll
        for(int r=0;r<4;r++){
          accR[r][m] += dot4(x, wr4[r]);
          accI[r][m] += dot4(x, wi4[r]);
        }
      }
    }
  }
  float brv[4], biv[4];
  #pragma unroll
  for(int r=0;r<4;r++){ brv[r]=br[o+16*r]; biv[r]=bi[o+16*r]; }
  #pragma unroll
  for(int m=0;m<4;m++){
    int node = node0 + grp*4 + m;
    if(node<N){
      #pragma unroll
      for(int r=0;r<4;r++){
        hrhi[node*HID + o + 16*r] =
          __floats2half2_rn(fmaxf(accR[r][m]+brv[r],0.f), fmaxf(accI[r][m]+biv[r],0.f));
      }
    }
  }
}

// CSR gather aggregation, 4 nodes per wave. Rows padded to multiples of 4, so
// each 4-edge block belongs to ONE node; bounds forced to SGPR so accumulator
// selection is a SCALAR branch (no exec-mask serialization).
__global__ __launch_bounds__(256) void k_agg(
    const int* __restrict__ rowptr, const float4* __restrict__ e4S,
    const __half2* __restrict__ hrhi, float* __restrict__ zrzi, int N){
  int lane = threadIdx.x & 63;
  int wid = blockIdx.x*(blockDim.x>>6) + (threadIdx.x>>6);
  int n0 = wid*4;
  if(n0>=N) return;
  int r0 = __builtin_amdgcn_readfirstlane(rowptr[n0]);
  int r1 = __builtin_amdgcn_readfirstlane(rowptr[min(n0+1,N)]);
  int r2 = __builtin_amdgcn_readfirstlane(rowptr[min(n0+2,N)]);
  int r3 = __builtin_amdgcn_readfirstlane(rowptr[min(n0+3,N)]);
  int r4 = __builtin_amdgcn_readfirstlane(rowptr[min(n0+4,N)]);
  float ar0=0.f,ai0=0.f, ar1=0.f,ai1=0.f, ar2=0.f,ai2=0.f, ar3=0.f,ai3=0.f;

  for(int jb=r0; jb<r4; jb+=4){
    float4 p0=e4S[jb], p1=e4S[jb+1], p2=e4S[jb+2], p3=e4S[jb+3];
    float2 v0=__half22float2(hrhi[__float_as_int(p0.x)*HID+lane]);
    float2 v1=__half22float2(hrhi[__float_as_int(p1.x)*HID+lane]);
    float2 v2=__half22float2(hrhi[__float_as_int(p2.x)*HID+lane]);
    float2 v3=__half22float2(hrhi[__float_as_int(p3.x)*HID+lane]);
    // block contribution in two independent chains (ILP), then one uniform add
    float cr0, ci0, cr1, ci1;
    cr0 = p0.y*v0.x;            cr0 = fmaf(-p0.z, v0.y, cr0);
    ci0 = p0.z*v0.x;            ci0 = fmaf( p0.y, v0.y, ci0);
    cr1 = p1.y*v1.x;            cr1 = fmaf(-p1.z, v1.y, cr1);
    ci1 = p1.z*v1.x;            ci1 = fmaf( p1.y, v1.y, ci1);
    cr0 = fmaf(p2.y, v2.x, cr0); cr0 = fmaf(-p2.z, v2.y, cr0);
    ci0 = fmaf(p2.z, v2.x, ci0); ci0 = fmaf( p2.y, v2.y, ci0);
    cr1 = fmaf(p3.y, v3.x, cr1); cr1 = fmaf(-p3.z, v3.y, cr1);
    ci1 = fmaf(p3.z, v3.x, ci1); ci1 = fmaf( p3.y, v3.y, ci1);
    float car = cr0 + cr1, cai = ci0 + ci1;
    if(jb < r1)      { ar0 += car; ai0 += cai; }
    else if(jb < r2) { ar1 += car; ai1 += cai; }
    else if(jb < r3) { ar2 += car; ai2 += cai; }
    else             { ar3 += car; ai3 += cai; }
  }

  if(n0+0<N) *(float2*)&zrzi[((n0+0)*HID+lane)*2] = make_float2(ar0, ai0);
  if(n0+1<N) *(float2*)&zrzi[((n0+1)*HID+lane)*2] = make_float2(ar1, ai1);
  if(n0+2<N) *(float2*)&zrzi[((n0+2)*HID+lane)*2] = make_float2(ar2, ai2);
  if(n0+3<N) *(float2*)&zrzi[((n0+3)*HID+lane)*2] = make_float2(ar3, ai3);
}

// fused complex dense layer; merged A/B/C pass + 4o x 4m register blocking.
// 256 thr = 16 o-lanes x 16 grps x 4 nodes; TN=64
__global__ __launch_bounds__(256) void k_dense(
    const float* __restrict__ W1, const float* __restrict__ b1,
    const float* __restrict__ W2, const float* __restrict__ b2,
    const float* __restrict__ zrzi, __half2* __restrict__ hrhi, int N){
  __shared__ float sW1[64*PAD], sW2[64*PAD], sZR[TN*PAD], sZI[TN*PAD];
  int tid = threadIdx.x;
  int o = tid & 15, grp = tid >> 4;
  int node0 = blockIdx.x*TN;
  #pragma unroll
  for(int t=0;t<4;t++){
    int f4 = tid + t*256; int row = f4>>4, kc = f4&15;
    *(float4*)&sW1[row*PAD + kc*4] = *(const float4*)&W1[row*HID + kc*4];
    *(float4*)&sW2[row*PAD + kc*4] = *(const float4*)&W2[row*HID + kc*4];
  }
  #pragma unroll
  for(int t=0;t<8;t++){
    int f4 = tid + t*256;         // 0..2047 over 64 nodes x 32 quads
    int nl = f4 >> 5, q = f4 & 31;
    int node = node0 + nl;
    float4 v = make_float4(0.f,0.f,0.f,0.f);
    if(node<N) v = *(const float4*)&zrzi[node*(2*HID) + q*4];
    sZR[nl*PAD + q*2]   = v.x;  sZI[nl*PAD + q*2]   = v.y;
    sZR[nl*PAD + q*2+1] = v.z;  sZI[nl*PAD + q*2+1] = v.w;
  }
  __syncthreads();

  float b1v[4], b2v[4];
  #pragma unroll
  for(int r=0;r<4;r++){ b1v[r]=b1[o+16*r]; b2v[r]=b2[o+16*r]; }

  // merged pass A/B/C: accA = zr.W1, accB = zi.W2, accC = zi.W1
  float zrn[4][4], accC[4][4];
  {
    float accA[4][4], accB[4][4];
    #pragma unroll
    for(int r=0;r<4;r++)
      #pragma unroll
      for(int m=0;m<4;m++){ accA[r][m]=0.f; accB[r][m]=0.f; accC[r][m]=0.f; }
    #pragma unroll 2
    for(int jc=0;jc<16;jc++){
      float4 w1[4], w2[4];
      #pragma unroll
      for(int r=0;r<4;r++){
        w1[r] = *(const float4*)&sW1[(o+16*r)*PAD + jc*4];
        w2[r] = *(const float4*)&sW2[(o+16*r)*PAD + jc*4];
      }
      #pragma unroll
      for(int m=0;m<4;m++){
        float4 xr = *(const float4*)&sZR[(grp*4+m)*PAD + jc*4];
        float4 xi = *(const float4*)&sZI[(grp*4+m)*PAD + jc*4];
        #pragma unroll
        for(int r=0;r<4;r++){
          accA[r][m] += dot4(xr, w1[r]);
          accB[r][m] += dot4(xi, w2[r]);
          accC[r][m] += dot4(xi, w1[r]);
        }
      }
    }
    #pragma unroll
    for(int r=0;r<4;r++)
      #pragma unroll
      for(int m=0;m<4;m++)
        zrn[r][m] = accA[r][m] + b1v[r] - accB[r][m] - b2v[r];
  }
  __syncthreads();                 // all reads of sZR done
  #pragma unroll
  for(int m=0;m<4;m++)
    #pragma unroll
    for(int r=0;r<4;r++)
      sZR[(grp*4+m)*PAD + o + 16*r] = zrn[r][m];   // pre-relu z_real_new tile
  __syncthreads();
  // pass D: accD = zrn . W2
  float accD[4][4];
  #pragma unroll
  for(int r=0;r<4;r++)
    #pragma unroll
    for(int m=0;m<4;m++) accD[r][m]=0.f;
  #pragma unroll 2
  for(int jc=0;jc<16;jc++){
    float4 w2[4];
    #pragma unroll
    for(int r=0;r<4;r++)
      w2[r] = *(const float4*)&sW2[(o+16*r)*PAD + jc*4];
    #pragma unroll
    for(int m=0;m<4;m++){
      float4 x = *(const float4*)&sZR[(grp*4+m)*PAD + jc*4];
      #pragma unroll
      for(int r=0;r<4;r++)
        accD[r][m] += dot4(x, w2[r]);
    }
  }
  #pragma unroll
  for(int m=0;m<4;m++){
    int node = node0 + grp*4 + m;
    if(node<N){
      #pragma unroll
      for(int r=0;r<4;r++){
        float zin = accD[r][m] + b2v[r] + accC[r][m] + b1v[r];
        hrhi[node*HID + o + 16*r] =
          __floats2half2_rn(fmaxf(zrn[r][m],0.f), fmaxf(zin,0.f));
      }
    }
  }
}

// logits (128->8) + log_softmax; 8 lanes per node; weights permuted to match
// interleaved (r,i) hrhi layout.
__global__ __launch_bounds__(256) void k_final(
    const __half2* __restrict__ hrhi, const float* __restrict__ t2W,
    const float* __restrict__ t2b, float* __restrict__ out, int N){
  __shared__ float sW[OUTC*132];   // sW[o][2d]=t2W[o][d], sW[o][2d+1]=t2W[o][64+d]
  int tid = threadIdx.x;
  #pragma unroll
  for(int t=0;t<4;t++){
    int idx = tid + t*256;          // 0..1023
    int o2 = idx >> 7, j = idx & 127;
    int dd = j >> 1, part = j & 1;
    sW[o2*132 + j] = t2W[o2*128 + part*64 + dd];
  }
  __syncthreads();
  int o = tid&7, nl = tid>>3;
  int node = blockIdx.x*32 + nl;
  float acc = 0.f;
  if(node<N){
    acc = t2b[o];
    const uint4* hp = reinterpret_cast<const uint4*>(&hrhi[node*HID]);
    #pragma unroll
    for(int q=0;q<16;q++){
      uint4 v = hp[q];              // 4 half2 = dims 4q..4q+3
      __half2 h0 = *reinterpret_cast<__half2*>(&v.x);
      __half2 h1 = *reinterpret_cast<__half2*>(&v.y);
      __half2 h2 = *reinterpret_cast<__half2*>(&v.z);
      __half2 h3 = *reinterpret_cast<__half2*>(&v.w);
      float2 f0 = __half22float2(h0), f1 = __half22float2(h1);
      float2 f2 = __half22float2(h2), f3 = __half22float2(h3);
      float4 w0 = *(const float4*)&sW[o*132 + q*8];
      float4 w1 = *(const float4*)&sW[o*132 + q*8 + 4];
      acc += dot4(make_float4(f0.x,f0.y,f1.x,f1.y), w0);
      acc += dot4(make_float4(f2.x,f2.y,f3.x,f3.y), w1);
    }
  }
  float mx = acc;
  #pragma unroll
  for(int msk=4; msk>=1; msk>>=1) mx = fmaxf(mx, __shfl_xor(mx, msk, 8));
  float e = expf(acc - mx);
  float sm = e;
  #pragma unroll
  for(int msk=4; msk>=1; msk>>=1) sm += __shfl_xor(sm, msk, 8);
  if(node<N) out[node*OUTC+o] = (acc - mx) - logf(sm);
}

extern "C" void kernel_launch(void* const* d_in, const int* in_sizes, int n_in,
                              void* d_out, int out_size, void* d_ws, size_t ws_size,
                              hipStream_t stream) {
  const float* h      = (const float*)d_in[0];
  const float* d      = (const float*)d_in[1];
  const float* w_real = (const float*)d_in[2];
  const float* w_imag = (const float*)d_in[3];
  const float* t1rW   = (const float*)d_in[4];
  const float* t1rb   = (const float*)d_in[5];
  const float* t1iW   = (const float*)d_in[6];
  const float* t1ib   = (const float*)d_in[7];
  const float* W1     = (const float*)d_in[8];
  const float* b1     = (const float*)d_in[9];
  const float* W2     = (const float*)d_in[10];
  const float* b2     = (const float*)d_in[11];
  const float* t2W    = (const float*)d_in[12];
  const float* t2b    = (const float*)d_in[13];
  const int*   src    = (const int*)d_in[14];
  const int*   dst    = (const int*)d_in[15];
  const int N = in_sizes[1];
  const int E = in_sizes[2];
  const int nLayers = in_sizes[8] / (HID*HID);
  float* out = (float*)d_out;

  char* w = (char*)d_ws;
  size_t off = 0;
  auto alloc = [&](size_t bytes)->void*{
    void* p = (void*)(w + off);
    off += (bytes + 255) & ~(size_t)255;
    return p;
  };
  __half2* hrhi   = (__half2*)alloc((size_t)N*HID*sizeof(__half2));
  float*  zrzi    = (float*)alloc((size_t)N*2*HID*4);
  int*    rowptr  = (int*)alloc((size_t)(N+1)*4);
  int*    cnt     = (int*)alloc((size_t)N*4);
  int*    rank    = (int*)alloc((size_t)E*4);
  float4* e4S     = (float4*)alloc(((size_t)E + 3*(size_t)N + 4)*16); // padded CSR
  int*    partials= (int*)alloc(2048);
  int*    total   = partials + 384;

  int nChunks = (N+255)/256;
  int eBlocks = (E+255)/256;
  int nTiles  = (N+TN-1)/TN;
  int aggWaves  = (N+3)/4;                 // 4 nodes per wave
  int aggBlocks = (aggWaves+3)/4;          // 4 waves per 256-thread block

  k_zero<<<nChunks, 256, 0, stream>>>(cnt, N);
  k_hist<<<eBlocks, 256, 0, stream>>>(dst, cnt, rank, E);
  k_scan1<<<nChunks, 256, 0, stream>>>(cnt, rowptr, partials, N);
  k_scan2<<<1, 256, 0, stream>>>(partials, total, nChunks);
  k_scan3<<<nChunks, 256, 0, stream>>>(rowptr, partials, total, N);
  k_fillpad<<<nChunks, 256, 0, stream>>>(cnt, rowptr, e4S, N);
  k_scatter<<<eBlocks, 256, 0, stream>>>(src, dst, d, w_real, w_imag,
                                         rowptr, rank, e4S, E);
  k_transform1<<<nTiles, 256, 0, stream>>>(h, t1rW, t1rb, t1iW, t1ib, hrhi, N);
  for(int i=0;i<nLayers;i++){
    k_agg<<<aggBlocks, 256, 0, stream>>>(rowptr, e4S, hrhi, zrzi, N);
    k_dense<<<nTiles, 256, 0, stream>>>(W1 + (size_t)i*HID*HID, b1 + (size_t)i*HID,
                                        W2 + (size_t)i*HID*HID, b2 + (size_t)i*HID,
                                        zrzi, hrhi, N);
  }
  k_final<<<(N+31)/32, 256, 0, stream>>>(hrhi, t2W, t2b, out, N);
}

// Round 8
// 324.951 us; speedup vs baseline: 3.8642x; 1.1355x over previous
//
#include <hip/hip_runtime.h>
#include <hip/hip_fp16.h>
#include <math.h>

#define HID 64
#define IN_DIM 128
#define OUTC 8
#define TN 64        // nodes per block in dense/transform kernels
#define HPAD 72      // padded row stride (halfs) for dense LDS (K=64)
#define TPAD 136     // padded row stride (halfs) for transform LDS (K=128)

typedef _Float16 h2_t __attribute__((ext_vector_type(2)));

static __device__ __forceinline__ float fdot2f(unsigned a, unsigned b, float c){
#if __has_builtin(__builtin_amdgcn_fdot2)
  return __builtin_amdgcn_fdot2(*(h2_t*)&a, *(h2_t*)&b, c, false);
#else
  __half2 ha = *(__half2*)&a, hb = *(__half2*)&b;
  float2 fa = __half22float2(ha), fb = __half22float2(hb);
  return fmaf(fa.x, fb.x, fmaf(fa.y, fb.y, c));
#endif
}

// dot of 8 fp16 pairs with fp32 accumulate
static __device__ __forceinline__ float dot8h(uint4 a, uint4 b, float acc){
  acc = fdot2f(a.x, b.x, acc);
  acc = fdot2f(a.y, b.y, acc);
  acc = fdot2f(a.z, b.z, acc);
  acc = fdot2f(a.w, b.w, acc);
  return acc;
}

static __device__ __forceinline__ uint2 pack4(float4 v){
  __half2 lo = __floats2half2_rn(v.x, v.y);
  __half2 hi = __floats2half2_rn(v.z, v.w);
  uint2 r; r.x = *(unsigned*)&lo; r.y = *(unsigned*)&hi; return r;
}

__global__ void k_zero(int* __restrict__ p, int n){
  int i = blockIdx.x*blockDim.x + threadIdx.x;
  if(i<n) p[i]=0;
}

// hist also records each edge's rank among same-dst edges (return of atomicAdd)
__global__ void k_hist(const int* __restrict__ dst, int* __restrict__ cnt,
                       int* __restrict__ rank, int E){
  int i = blockIdx.x*blockDim.x + threadIdx.x;
  if(i<E) rank[i] = atomicAdd(&cnt[dst[i]], 1);
}

// per-chunk exclusive scan of PADDED counts -> rowptr(chunk-local), chunk sums
__global__ void k_scan1(const int* __restrict__ cnt, int* __restrict__ rowptr,
                        int* __restrict__ partials, int n){
  __shared__ int s[256];
  int tid = threadIdx.x; int gid = blockIdx.x*256 + tid;
  int v = (gid<n)? ((cnt[gid]+3)&~3) : 0;   // pad each row to multiple of 4
  s[tid] = v; __syncthreads();
  #pragma unroll
  for(int off=1; off<256; off<<=1){
    int t = (tid>=off)? s[tid-off] : 0; __syncthreads();
    s[tid] += t; __syncthreads();
  }
  if(gid<n) rowptr[gid] = s[tid] - v;       // exclusive within chunk
  if(tid==255) partials[blockIdx.x] = s[255];
}

__global__ void k_scan2(int* __restrict__ partials, int* __restrict__ total, int np){
  __shared__ int s[256];
  int tid = threadIdx.x;
  int v = (tid<np)? partials[tid] : 0;
  s[tid] = v; __syncthreads();
  #pragma unroll
  for(int off=1; off<256; off<<=1){
    int t = (tid>=off)? s[tid-off] : 0; __syncthreads();
    s[tid] += t; __syncthreads();
  }
  if(tid==np-1) *total = s[tid];            // padded edge total
  if(tid<np) partials[tid] = s[tid] - v;    // exclusive
}

__global__ void k_scan3(int* __restrict__ rowptr, const int* __restrict__ partials,
                        const int* __restrict__ total, int n){
  int gid = blockIdx.x*256 + threadIdx.x;
  if(gid<n) rowptr[gid] += partials[blockIdx.x];
  if(gid==0) rowptr[n] = *total;
}

// zero-fill the <=3 pad slots per node (dummy edges: src=0, er=ei=0)
__global__ void k_fillpad(const int* __restrict__ cnt, const int* __restrict__ rowptr,
                          float4* __restrict__ e4S, int N){
  int n = blockIdx.x*blockDim.x + threadIdx.x;
  if(n>=N) return;
  int p = rowptr[n] + cnt[n], e = rowptr[n+1];
  for(; p<e; ++p) e4S[p] = make_float4(0.f,0.f,0.f,0.f);
}

// packed payload: e4S[p] = { bits(src), e_real, e_imag, 0 }; position is
// rowptr[dst] + rank  (NO atomics here — rank captured in k_hist)
__global__ void k_scatter(const int* __restrict__ src, const int* __restrict__ dst,
                          const float* __restrict__ d, const float* __restrict__ wr,
                          const float* __restrict__ wi,
                          const int* __restrict__ rowptr, const int* __restrict__ rank,
                          float4* __restrict__ e4S, int E){
  int i = blockIdx.x*blockDim.x + threadIdx.x;
  if(i>=E) return;
  int s = src[i], t = dst[i];
  float dd = d[t]*d[s];
  int p = rowptr[t] + rank[i];
  e4S[p] = make_float4(__int_as_float(s), dd*wr[i], dd*wi[i], 0.f);
}

// h[N,128] -> hrhi[node*64+o] = half2(relu(h@Wr.T+br), relu(h@Wi.T+bi))
// fp16 LDS + fdot2; 256 thr = 16 o-lanes x 16 grps x 4 nodes; TN=64, K=128
__global__ __launch_bounds__(256, 3) void k_transform1(
    const float* __restrict__ h, const float* __restrict__ Wr, const float* __restrict__ br,
    const float* __restrict__ Wi, const float* __restrict__ bi,
    __half2* __restrict__ hrhi, int N){
  __shared__ __align__(16) __half sWrh[64*TPAD], sWih[64*TPAD], sXh[TN*TPAD];
  int tid = threadIdx.x;
  int o = tid & 15, grp = tid >> 4;
  int node0 = blockIdx.x*TN;
  // stage weights [64][128] fp32 -> fp16
  #pragma unroll
  for(int t=0;t<8;t++){
    int f4 = tid + t*256; int row = f4>>5, kc = f4&31;
    *(uint2*)&sWrh[row*TPAD + kc*4] = pack4(*(const float4*)&Wr[row*IN_DIM + kc*4]);
    *(uint2*)&sWih[row*TPAD + kc*4] = pack4(*(const float4*)&Wi[row*IN_DIM + kc*4]);
  }
  // stage X [64][128] fp32 -> fp16
  #pragma unroll
  for(int t=0;t<8;t++){
    int f4 = tid + t*256; int nl = f4>>5, q = f4&31;
    int node = node0 + nl;
    float4 x = make_float4(0.f,0.f,0.f,0.f);
    if(node<N) x = *(const float4*)&h[node*IN_DIM + q*4];
    *(uint2*)&sXh[nl*TPAD + q*4] = pack4(x);
  }
  __syncthreads();
  float accR[4][4], accI[4][4];
  #pragma unroll
  for(int r=0;r<4;r++)
    #pragma unroll
    for(int m=0;m<4;m++){ accR[r][m]=0.f; accI[r][m]=0.f; }
  #pragma unroll 2
  for(int c=0;c<16;c++){
    uint4 wr4[4], wi4[4];
    #pragma unroll
    for(int r=0;r<4;r++){
      wr4[r] = *(const uint4*)&sWrh[(o+16*r)*TPAD + c*8];
      wi4[r] = *(const uint4*)&sWih[(o+16*r)*TPAD + c*8];
    }
    #pragma unroll
    for(int m=0;m<4;m++){
      uint4 x = *(const uint4*)&sXh[(grp*4+m)*TPAD + c*8];
      #pragma unroll
      for(int r=0;r<4;r++){
        accR[r][m] = dot8h(x, wr4[r], accR[r][m]);
        accI[r][m] = dot8h(x, wi4[r], accI[r][m]);
      }
    }
  }
  float brv[4], biv[4];
  #pragma unroll
  for(int r=0;r<4;r++){ brv[r]=br[o+16*r]; biv[r]=bi[o+16*r]; }
  #pragma unroll
  for(int m=0;m<4;m++){
    int node = node0 + grp*4 + m;
    if(node<N){
      #pragma unroll
      for(int r=0;r<4;r++){
        hrhi[node*HID + o + 16*r] =
          __floats2half2_rn(fmaxf(accR[r][m]+brv[r],0.f), fmaxf(accI[r][m]+biv[r],0.f));
      }
    }
  }
}

// CSR gather aggregation, 4 nodes per wave. Rows padded to multiples of 4, so
// each 4-edge block belongs to ONE node; bounds forced to SGPR so accumulator
// selection is a SCALAR branch (no exec-mask serialization).
__global__ __launch_bounds__(256) void k_agg(
    const int* __restrict__ rowptr, const float4* __restrict__ e4S,
    const __half2* __restrict__ hrhi, float* __restrict__ zrzi, int N){
  int lane = threadIdx.x & 63;
  int wid = blockIdx.x*(blockDim.x>>6) + (threadIdx.x>>6);
  int n0 = wid*4;
  if(n0>=N) return;
  int r0 = __builtin_amdgcn_readfirstlane(rowptr[n0]);
  int r1 = __builtin_amdgcn_readfirstlane(rowptr[min(n0+1,N)]);
  int r2 = __builtin_amdgcn_readfirstlane(rowptr[min(n0+2,N)]);
  int r3 = __builtin_amdgcn_readfirstlane(rowptr[min(n0+3,N)]);
  int r4 = __builtin_amdgcn_readfirstlane(rowptr[min(n0+4,N)]);
  float ar0=0.f,ai0=0.f, ar1=0.f,ai1=0.f, ar2=0.f,ai2=0.f, ar3=0.f,ai3=0.f;

  for(int jb=r0; jb<r4; jb+=4){
    float4 p0=e4S[jb], p1=e4S[jb+1], p2=e4S[jb+2], p3=e4S[jb+3];
    float2 v0=__half22float2(hrhi[__float_as_int(p0.x)*HID+lane]);
    float2 v1=__half22float2(hrhi[__float_as_int(p1.x)*HID+lane]);
    float2 v2=__half22float2(hrhi[__float_as_int(p2.x)*HID+lane]);
    float2 v3=__half22float2(hrhi[__float_as_int(p3.x)*HID+lane]);
    // block contribution in two independent chains (ILP), then one uniform add
    float cr0, ci0, cr1, ci1;
    cr0 = p0.y*v0.x;            cr0 = fmaf(-p0.z, v0.y, cr0);
    ci0 = p0.z*v0.x;            ci0 = fmaf( p0.y, v0.y, ci0);
    cr1 = p1.y*v1.x;            cr1 = fmaf(-p1.z, v1.y, cr1);
    ci1 = p1.z*v1.x;            ci1 = fmaf( p1.y, v1.y, ci1);
    cr0 = fmaf(p2.y, v2.x, cr0); cr0 = fmaf(-p2.z, v2.y, cr0);
    ci0 = fmaf(p2.z, v2.x, ci0); ci0 = fmaf( p2.y, v2.y, ci0);
    cr1 = fmaf(p3.y, v3.x, cr1); cr1 = fmaf(-p3.z, v3.y, cr1);
    ci1 = fmaf(p3.z, v3.x, ci1); ci1 = fmaf( p3.y, v3.y, ci1);
    float car = cr0 + cr1, cai = ci0 + ci1;
    if(jb < r1)      { ar0 += car; ai0 += cai; }
    else if(jb < r2) { ar1 += car; ai1 += cai; }
    else if(jb < r3) { ar2 += car; ai2 += cai; }
    else             { ar3 += car; ai3 += cai; }
  }

  if(n0+0<N) *(float2*)&zrzi[((n0+0)*HID+lane)*2] = make_float2(ar0, ai0);
  if(n0+1<N) *(float2*)&zrzi[((n0+1)*HID+lane)*2] = make_float2(ar1, ai1);
  if(n0+2<N) *(float2*)&zrzi[((n0+2)*HID+lane)*2] = make_float2(ar2, ai2);
  if(n0+3<N) *(float2*)&zrzi[((n0+3)*HID+lane)*2] = make_float2(ar3, ai3);
}

// fused complex dense layer; fp16 LDS + fdot2, merged A/B/C pass.
// 256 thr = 16 o-lanes x 16 grps x 4 nodes; TN=64
__global__ __launch_bounds__(256, 4) void k_dense(
    const float* __restrict__ W1, const float* __restrict__ b1,
    const float* __restrict__ W2, const float* __restrict__ b2,
    const float* __restrict__ zrzi, __half2* __restrict__ hrhi, int N){
  __shared__ __align__(16) __half sW1h[64*HPAD], sW2h[64*HPAD];
  __shared__ __align__(16) __half sZRh[TN*HPAD], sZIh[TN*HPAD];
  int tid = threadIdx.x;
  int o = tid & 15, grp = tid >> 4;
  int node0 = blockIdx.x*TN;
  // stage weights [64][64] fp32 -> fp16
  #pragma unroll
  for(int t=0;t<4;t++){
    int f4 = tid + t*256; int row = f4>>4, kc = f4&15;
    *(uint2*)&sW1h[row*HPAD + kc*4] = pack4(*(const float4*)&W1[row*HID + kc*4]);
    *(uint2*)&sW2h[row*HPAD + kc*4] = pack4(*(const float4*)&W2[row*HID + kc*4]);
  }
  // stage zr/zi: zrzi[node][2k..2k+1] interleaved fp32 -> split fp16 tiles
  #pragma unroll
  for(int t=0;t<8;t++){
    int f4 = tid + t*256;         // 0..2047 over 64 nodes x 32 quads
    int nl = f4 >> 5, q = f4 & 31;
    int node = node0 + nl;
    float4 v = make_float4(0.f,0.f,0.f,0.f);
    if(node<N) v = *(const float4*)&zrzi[node*(2*HID) + q*4];
    __half2 zr2 = __floats2half2_rn(v.x, v.z);   // zr[2q], zr[2q+1]
    __half2 zi2 = __floats2half2_rn(v.y, v.w);   // zi[2q], zi[2q+1]
    *(unsigned*)&sZRh[nl*HPAD + q*2] = *(unsigned*)&zr2;
    *(unsigned*)&sZIh[nl*HPAD + q*2] = *(unsigned*)&zi2;
  }
  __syncthreads();

  float b1v[4], b2v[4];
  #pragma unroll
  for(int r=0;r<4;r++){ b1v[r]=b1[o+16*r]; b2v[r]=b2[o+16*r]; }

  // merged pass A/B/C: accA = zr.W1, accB = zi.W2, accC = zi.W1
  float zrn[4][4], accC[4][4];
  {
    float accA[4][4], accB[4][4];
    #pragma unroll
    for(int r=0;r<4;r++)
      #pragma unroll
      for(int m=0;m<4;m++){ accA[r][m]=0.f; accB[r][m]=0.f; accC[r][m]=0.f; }
    #pragma unroll 2
    for(int c=0;c<8;c++){
      uint4 w1v[4], w2v[4];
      #pragma unroll
      for(int r=0;r<4;r++){
        w1v[r] = *(const uint4*)&sW1h[(o+16*r)*HPAD + c*8];
        w2v[r] = *(const uint4*)&sW2h[(o+16*r)*HPAD + c*8];
      }
      #pragma unroll
      for(int m=0;m<4;m++){
        uint4 xr = *(const uint4*)&sZRh[(grp*4+m)*HPAD + c*8];
        uint4 xi = *(const uint4*)&sZIh[(grp*4+m)*HPAD + c*8];
        #pragma unroll
        for(int r=0;r<4;r++){
          accA[r][m] = dot8h(xr, w1v[r], accA[r][m]);
          accB[r][m] = dot8h(xi, w2v[r], accB[r][m]);
          accC[r][m] = dot8h(xi, w1v[r], accC[r][m]);
        }
      }
    }
    #pragma unroll
    for(int r=0;r<4;r++)
      #pragma unroll
      for(int m=0;m<4;m++)
        zrn[r][m] = accA[r][m] + b1v[r] - accB[r][m] - b2v[r];
  }
  __syncthreads();                 // all reads of sZRh done
  #pragma unroll
  for(int m=0;m<4;m++)
    #pragma unroll
    for(int r=0;r<4;r++)
      sZRh[(grp*4+m)*HPAD + o + 16*r] = __float2half(zrn[r][m]); // pre-relu zrn
  __syncthreads();
  // pass D: accD = zrn . W2
  float accD[4][4];
  #pragma unroll
  for(int r=0;r<4;r++)
    #pragma unroll
    for(int m=0;m<4;m++) accD[r][m]=0.f;
  #pragma unroll 2
  for(int c=0;c<8;c++){
    uint4 w2v[4];
    #pragma unroll
    for(int r=0;r<4;r++)
      w2v[r] = *(const uint4*)&sW2h[(o+16*r)*HPAD + c*8];
    #pragma unroll
    for(int m=0;m<4;m++){
      uint4 x = *(const uint4*)&sZRh[(grp*4+m)*HPAD + c*8];
      #pragma unroll
      for(int r=0;r<4;r++)
        accD[r][m] = dot8h(x, w2v[r], accD[r][m]);
    }
  }
  #pragma unroll
  for(int m=0;m<4;m++){
    int node = node0 + grp*4 + m;
    if(node<N){
      #pragma unroll
      for(int r=0;r<4;r++){
        float zin = accD[r][m] + b2v[r] + accC[r][m] + b1v[r];
        hrhi[node*HID + o + 16*r] =
          __floats2half2_rn(fmaxf(zrn[r][m],0.f), fmaxf(zin,0.f));
      }
    }
  }
}

// logits (128->8) + log_softmax; 8 lanes per node; weights permuted to match
// interleaved (r,i) hrhi layout.
__global__ __launch_bounds__(256) void k_final(
    const __half2* __restrict__ hrhi, const float* __restrict__ t2W,
    const float* __restrict__ t2b, float* __restrict__ out, int N){
  __shared__ float sW[OUTC*132];   // sW[o][2d]=t2W[o][d], sW[o][2d+1]=t2W[o][64+d]
  int tid = threadIdx.x;
  #pragma unroll
  for(int t=0;t<4;t++){
    int idx = tid + t*256;          // 0..1023
    int o2 = idx >> 7, j = idx & 127;
    int dd = j >> 1, part = j & 1;
    sW[o2*132 + j] = t2W[o2*128 + part*64 + dd];
  }
  __syncthreads();
  int o = tid&7, nl = tid>>3;
  int node = blockIdx.x*32 + nl;
  float acc = 0.f;
  if(node<N){
    acc = t2b[o];
    const uint4* hp = reinterpret_cast<const uint4*>(&hrhi[node*HID]);
    #pragma unroll
    for(int q=0;q<16;q++){
      uint4 v = hp[q];              // 4 half2 = dims 4q..4q+3
      __half2 h0 = *reinterpret_cast<__half2*>(&v.x);
      __half2 h1 = *reinterpret_cast<__half2*>(&v.y);
      __half2 h2 = *reinterpret_cast<__half2*>(&v.z);
      __half2 h3 = *reinterpret_cast<__half2*>(&v.w);
      float2 f0 = __half22float2(h0), f1 = __half22float2(h1);
      float2 f2 = __half22float2(h2), f3 = __half22float2(h3);
      float4 w0 = *(const float4*)&sW[o*132 + q*8];
      float4 w1 = *(const float4*)&sW[o*132 + q*8 + 4];
      acc += fmaf(f0.x,w0.x, fmaf(f0.y,w0.y, fmaf(f1.x,w0.z, f1.y*w0.w)));
      acc += fmaf(f2.x,w1.x, fmaf(f2.y,w1.y, fmaf(f3.x,w1.z, f3.y*w1.w)));
    }
  }
  float mx = acc;
  #pragma unroll
  for(int msk=4; msk>=1; msk>>=1) mx = fmaxf(mx, __shfl_xor(mx, msk, 8));
  float e = expf(acc - mx);
  float sm = e;
  #pragma unroll
  for(int msk=4; msk>=1; msk>>=1) sm += __shfl_xor(sm, msk, 8);
  if(node<N) out[node*OUTC+o] = (acc - mx) - logf(sm);
}

extern "C" void kernel_launch(void* const* d_in, const int* in_sizes, int n_in,
                              void* d_out, int out_size, void* d_ws, size_t ws_size,
                              hipStream_t stream) {
  const float* h      = (const float*)d_in[0];
  const float* d      = (const float*)d_in[1];
  const float* w_real = (const float*)d_in[2];
  const float* w_imag = (const float*)d_in[3];
  const float* t1rW   = (const float*)d_in[4];
  const float* t1rb   = (const float*)d_in[5];
  const float* t1iW   = (const float*)d_in[6];
  const float* t1ib   = (const float*)d_in[7];
  const float* W1     = (const float*)d_in[8];
  const float* b1     = (const float*)d_in[9];
  const float* W2     = (const float*)d_in[10];
  const float* b2     = (const float*)d_in[11];
  const float* t2W    = (const float*)d_in[12];
  const float* t2b    = (const float*)d_in[13];
  const int*   src    = (const int*)d_in[14];
  const int*   dst    = (const int*)d_in[15];
  const int N = in_sizes[1];
  const int E = in_sizes[2];
  const int nLayers = in_sizes[8] / (HID*HID);
  float* out = (float*)d_out;

  char* w = (char*)d_ws;
  size_t off = 0;
  auto alloc = [&](size_t bytes)->void*{
    void* p = (void*)(w + off);
    off += (bytes + 255) & ~(size_t)255;
    return p;
  };
  __half2* hrhi   = (__half2*)alloc((size_t)N*HID*sizeof(__half2));
  float*  zrzi    = (float*)alloc((size_t)N*2*HID*4);
  int*    rowptr  = (int*)alloc((size_t)(N+1)*4);
  int*    cnt     = (int*)alloc((size_t)N*4);
  int*    rank    = (int*)alloc((size_t)E*4);
  float4* e4S     = (float4*)alloc(((size_t)E + 3*(size_t)N + 4)*16); // padded CSR
  int*    partials= (int*)alloc(2048);
  int*    total   = partials + 384;

  int nChunks = (N+255)/256;
  int eBlocks = (E+255)/256;
  int nTiles  = (N+TN-1)/TN;
  int aggWaves  = (N+3)/4;                 // 4 nodes per wave
  int aggBlocks = (aggWaves+3)/4;          // 4 waves per 256-thread block

  k_zero<<<nChunks, 256, 0, stream>>>(cnt, N);
  k_hist<<<eBlocks, 256, 0, stream>>>(dst, cnt, rank, E);
  k_scan1<<<nChunks, 256, 0, stream>>>(cnt, rowptr, partials, N);
  k_scan2<<<1, 256, 0, stream>>>(partials, total, nChunks);
  k_scan3<<<nChunks, 256, 0, stream>>>(rowptr, partials, total, N);
  k_fillpad<<<nChunks, 256, 0, stream>>>(cnt, rowptr, e4S, N);
  k_scatter<<<eBlocks, 256, 0, stream>>>(src, dst, d, w_real, w_imag,
                                         rowptr, rank, e4S, E);
  k_transform1<<<nTiles, 256, 0, stream>>>(h, t1rW, t1rb, t1iW, t1ib, hrhi, N);
  for(int i=0;i<nLayers;i++){
    k_agg<<<aggBlocks, 256, 0, stream>>>(rowptr, e4S, hrhi, zrzi, N);
    k_dense<<<nTiles, 256, 0, stream>>>(W1 + (size_t)i*HID*HID, b1 + (size_t)i*HID,
                                        W2 + (size_t)i*HID*HID, b2 + (size_t)i*HID,
                                        zrzi, hrhi, N);
  }
  k_final<<<(N+31)/32, 256, 0, stream>>>(hrhi, t2W, t2b, out, N);
}

// Round 10
// 309.297 us; speedup vs baseline: 4.0597x; 1.0506x over previous
//
#include <hip/hip_runtime.h>
#include <hip/hip_fp16.h>
#include <math.h>

#define HID 64
#define IN_DIM 128
#define OUTC 8
#define TN 64        // nodes per block in dense/transform kernels
#define HPAD 72      // padded row stride (halfs) for dense LDS (K=64)
#define TPAD 136     // padded row stride (halfs) for transform LDS (K=128)

typedef _Float16 h2_t __attribute__((ext_vector_type(2)));

static __device__ __forceinline__ float fdot2f(unsigned a, unsigned b, float c){
#if __has_builtin(__builtin_amdgcn_fdot2)
  return __builtin_amdgcn_fdot2(*(h2_t*)&a, *(h2_t*)&b, c, false);
#else
  __half2 ha = *(__half2*)&a, hb = *(__half2*)&b;
  float2 fa = __half22float2(ha), fb = __half22float2(hb);
  return fmaf(fa.x, fb.x, fmaf(fa.y, fb.y, c));
#endif
}

// dot of 8 fp16 pairs with fp32 accumulate
static __device__ __forceinline__ float dot8h(uint4 a, uint4 b, float acc){
  acc = fdot2f(a.x, b.x, acc);
  acc = fdot2f(a.y, b.y, acc);
  acc = fdot2f(a.z, b.z, acc);
  acc = fdot2f(a.w, b.w, acc);
  return acc;
}

static __device__ __forceinline__ uint2 pack4(float4 v){
  __half2 lo = __floats2half2_rn(v.x, v.y);
  __half2 hi = __floats2half2_rn(v.z, v.w);
  uint2 r; r.x = *(unsigned*)&lo; r.y = *(unsigned*)&hi; return r;
}

__global__ void k_zero(int* __restrict__ p, int n){
  int i = blockIdx.x*blockDim.x + threadIdx.x;
  if(i<n) p[i]=0;
}

// hist also records each edge's rank among same-dst edges (return of atomicAdd)
__global__ void k_hist(const int* __restrict__ dst, int* __restrict__ cnt,
                       int* __restrict__ rank, int E){
  int i = blockIdx.x*blockDim.x + threadIdx.x;
  if(i<E) rank[i] = atomicAdd(&cnt[dst[i]], 1);
}

// per-chunk exclusive scan of PADDED counts -> rowptr(chunk-local), chunk sums
__global__ void k_scan1(const int* __restrict__ cnt, int* __restrict__ rowptr,
                        int* __restrict__ partials, int n){
  __shared__ int s[256];
  int tid = threadIdx.x; int gid = blockIdx.x*256 + tid;
  int v = (gid<n)? ((cnt[gid]+3)&~3) : 0;   // pad each row to multiple of 4
  s[tid] = v; __syncthreads();
  #pragma unroll
  for(int off=1; off<256; off<<=1){
    int t = (tid>=off)? s[tid-off] : 0; __syncthreads();
    s[tid] += t; __syncthreads();
  }
  if(gid<n) rowptr[gid] = s[tid] - v;       // exclusive within chunk
  if(tid==255) partials[blockIdx.x] = s[255];
}

// merged scan2+scan3: every block redundantly scans the (<=256) chunk sums,
// adds its own chunk prefix, and block 0 writes the padded total to rowptr[n].
__global__ void k_scan3(int* __restrict__ rowptr, const int* __restrict__ partials,
                        int n, int np){
  __shared__ int s[256];
  __shared__ int sBase, sTot;
  int tid = threadIdx.x;
  int v = (tid<np)? partials[tid] : 0;
  s[tid] = v; __syncthreads();
  #pragma unroll
  for(int off=1; off<256; off<<=1){
    int t = (tid>=off)? s[tid-off] : 0; __syncthreads();
    s[tid] += t; __syncthreads();
  }
  if(tid==255) sTot = s[255];
  if(tid==blockIdx.x) sBase = s[tid] - v;   // exclusive prefix of own chunk
  __syncthreads();
  int gid = blockIdx.x*256 + tid;
  if(gid<n) rowptr[gid] += sBase;
  if(blockIdx.x==0 && tid==0) rowptr[n] = sTot;
}

// zero-fill the <=3 pad slots per node (dummy edges: src=0, er=ei=0)
__global__ void k_fillpad(const int* __restrict__ cnt, const int* __restrict__ rowptr,
                          uint2* __restrict__ eS, int N){
  int n = blockIdx.x*blockDim.x + threadIdx.x;
  if(n>=N) return;
  int p = rowptr[n] + cnt[n], e = rowptr[n+1];
  for(; p<e; ++p) eS[p] = make_uint2(0u, 0u);
}

// packed 8B payload: eS[p] = { src, half2(e_real, e_imag) }; position is
// rowptr[dst] + rank  (NO atomics here — rank captured in k_hist)
__global__ void k_scatter(const int* __restrict__ src, const int* __restrict__ dst,
                          const float* __restrict__ d, const float* __restrict__ wr,
                          const float* __restrict__ wi,
                          const int* __restrict__ rowptr, const int* __restrict__ rank,
                          uint2* __restrict__ eS, int E){
  int i = blockIdx.x*blockDim.x + threadIdx.x;
  if(i>=E) return;
  int s = src[i], t = dst[i];
  float dd = d[t]*d[s];
  int p = rowptr[t] + rank[i];
  __half2 e2 = __floats2half2_rn(dd*wr[i], dd*wi[i]);
  uint2 q; q.x = (unsigned)s; q.y = *(unsigned*)&e2;
  eS[p] = q;
}

// h[N,128] -> hrhi[node*64+o] = half2(relu(h@Wr.T+br), relu(h@Wi.T+bi))
// fp16 LDS + fdot2; 256 thr = 16 o-lanes x 16 grps x 4 nodes; TN=64, K=128
__global__ __launch_bounds__(256, 3) void k_transform1(
    const float* __restrict__ h, const float* __restrict__ Wr, const float* __restrict__ br,
    const float* __restrict__ Wi, const float* __restrict__ bi,
    __half2* __restrict__ hrhi, int N){
  __shared__ __align__(16) __half sWrh[64*TPAD], sWih[64*TPAD], sXh[TN*TPAD];
  int tid = threadIdx.x;
  int o = tid & 15, grp = tid >> 4;
  int node0 = blockIdx.x*TN;
  // stage weights [64][128] fp32 -> fp16
  #pragma unroll
  for(int t=0;t<8;t++){
    int f4 = tid + t*256; int row = f4>>5, kc = f4&31;
    *(uint2*)&sWrh[row*TPAD + kc*4] = pack4(*(const float4*)&Wr[row*IN_DIM + kc*4]);
    *(uint2*)&sWih[row*TPAD + kc*4] = pack4(*(const float4*)&Wi[row*IN_DIM + kc*4]);
  }
  // stage X [64][128] fp32 -> fp16
  #pragma unroll
  for(int t=0;t<8;t++){
    int f4 = tid + t*256; int nl = f4>>5, q = f4&31;
    int node = node0 + nl;
    float4 x = make_float4(0.f,0.f,0.f,0.f);
    if(node<N) x = *(const float4*)&h[node*IN_DIM + q*4];
    *(uint2*)&sXh[nl*TPAD + q*4] = pack4(x);
  }
  __syncthreads();
  float accR[4][4], accI[4][4];
  #pragma unroll
  for(int r=0;r<4;r++)
    #pragma unroll
    for(int m=0;m<4;m++){ accR[r][m]=0.f; accI[r][m]=0.f; }
  #pragma unroll 2
  for(int c=0;c<16;c++){
    uint4 wr4[4], wi4[4];
    #pragma unroll
    for(int r=0;r<4;r++){
      wr4[r] = *(const uint4*)&sWrh[(o+16*r)*TPAD + c*8];
      wi4[r] = *(const uint4*)&sWih[(o+16*r)*TPAD + c*8];
    }
    #pragma unroll
    for(int m=0;m<4;m++){
      uint4 x = *(const uint4*)&sXh[(grp*4+m)*TPAD + c*8];
      #pragma unroll
      for(int r=0;r<4;r++){
        accR[r][m] = dot8h(x, wr4[r], accR[r][m]);
        accI[r][m] = dot8h(x, wi4[r], accI[r][m]);
      }
    }
  }
  float brv[4], biv[4];
  #pragma unroll
  for(int r=0;r<4;r++){ brv[r]=br[o+16*r]; biv[r]=bi[o+16*r]; }
  #pragma unroll
  for(int m=0;m<4;m++){
    int node = node0 + grp*4 + m;
    if(node<N){
      #pragma unroll
      for(int r=0;r<4;r++){
        hrhi[node*HID + o + 16*r] =
          __floats2half2_rn(fmaxf(accR[r][m]+brv[r],0.f), fmaxf(accI[r][m]+biv[r],0.f));
      }
    }
  }
}

// CSR gather aggregation, 4 nodes per wave, 8 edges per iteration (two 4-blocks)
// -> 8 gathers + 8 scalar payload loads in flight. Rows padded to multiple of 4;
// bounds in SGPR so accumulator selection is a scalar branch.
__global__ __launch_bounds__(256) void k_agg(
    const int* __restrict__ rowptr, const uint2* __restrict__ eS,
    const __half2* __restrict__ hrhi, float* __restrict__ zrzi, int N){
  int lane = threadIdx.x & 63;
  int wid = blockIdx.x*(blockDim.x>>6) + (threadIdx.x>>6);
  int n0 = wid*4;
  if(n0>=N) return;
  int r0 = __builtin_amdgcn_readfirstlane(rowptr[n0]);
  int r1 = __builtin_amdgcn_readfirstlane(rowptr[min(n0+1,N)]);
  int r2 = __builtin_amdgcn_readfirstlane(rowptr[min(n0+2,N)]);
  int r3 = __builtin_amdgcn_readfirstlane(rowptr[min(n0+3,N)]);
  int r4 = __builtin_amdgcn_readfirstlane(rowptr[min(n0+4,N)]);
  float ar0=0.f,ai0=0.f, ar1=0.f,ai1=0.f, ar2=0.f,ai2=0.f, ar3=0.f,ai3=0.f;

#define SELADD(J, car, cai)                          \
  if((J)<r1)      { ar0+=car; ai0+=cai; }            \
  else if((J)<r2) { ar1+=car; ai1+=cai; }            \
  else if((J)<r3) { ar2+=car; ai2+=cai; }            \
  else            { ar3+=car; ai3+=cai; }

#define BLK4(Q0,Q1,Q2,Q3,V0,V1,V2,V3,J)                               \
  {                                                                   \
    float2 e0=__half22float2(*(const __half2*)&Q0.y);                 \
    float2 e1=__half22float2(*(const __half2*)&Q1.y);                 \
    float2 e2=__half22float2(*(const __half2*)&Q2.y);                 \
    float2 e3=__half22float2(*(const __half2*)&Q3.y);                 \
    float cr0, ci0, cr1, ci1;                                         \
    cr0 = e0.x*V0.x;             cr0 = fmaf(-e0.y, V0.y, cr0);        \
    ci0 = e0.y*V0.x;             ci0 = fmaf( e0.x, V0.y, ci0);        \
    cr1 = e1.x*V1.x;             cr1 = fmaf(-e1.y, V1.y, cr1);        \
    ci1 = e1.y*V1.x;             ci1 = fmaf( e1.x, V1.y, ci1);        \
    cr0 = fmaf(e2.x, V2.x, cr0); cr0 = fmaf(-e2.y, V2.y, cr0);        \
    ci0 = fmaf(e2.y, V2.x, ci0); ci0 = fmaf( e2.x, V2.y, ci0);        \
    cr1 = fmaf(e3.x, V3.x, cr1); cr1 = fmaf(-e3.y, V3.y, cr1);        \
    ci1 = fmaf(e3.y, V3.x, ci1); ci1 = fmaf( e3.x, V3.y, ci1);        \
    float car = cr0 + cr1, cai = ci0 + ci1;                           \
    SELADD(J, car, cai);                                              \
  }

  int jb = r0;
  for(; jb+8<=r4; jb+=8){
    uint2 qa0=eS[jb  ], qa1=eS[jb+1], qa2=eS[jb+2], qa3=eS[jb+3];
    uint2 qb0=eS[jb+4], qb1=eS[jb+5], qb2=eS[jb+6], qb3=eS[jb+7];
    float2 va0=__half22float2(hrhi[(int)qa0.x*HID+lane]);
    float2 va1=__half22float2(hrhi[(int)qa1.x*HID+lane]);
    float2 va2=__half22float2(hrhi[(int)qa2.x*HID+lane]);
    float2 va3=__half22float2(hrhi[(int)qa3.x*HID+lane]);
    float2 vb0=__half22float2(hrhi[(int)qb0.x*HID+lane]);
    float2 vb1=__half22float2(hrhi[(int)qb1.x*HID+lane]);
    float2 vb2=__half22float2(hrhi[(int)qb2.x*HID+lane]);
    float2 vb3=__half22float2(hrhi[(int)qb3.x*HID+lane]);
    BLK4(qa0,qa1,qa2,qa3, va0,va1,va2,va3, jb);
    BLK4(qb0,qb1,qb2,qb3, vb0,vb1,vb2,vb3, jb+4);
  }
  if(jb<r4){
    uint2 q0=eS[jb], q1=eS[jb+1], q2=eS[jb+2], q3=eS[jb+3];
    float2 v0=__half22float2(hrhi[(int)q0.x*HID+lane]);
    float2 v1=__half22float2(hrhi[(int)q1.x*HID+lane]);
    float2 v2=__half22float2(hrhi[(int)q2.x*HID+lane]);
    float2 v3=__half22float2(hrhi[(int)q3.x*HID+lane]);
    BLK4(q0,q1,q2,q3, v0,v1,v2,v3, jb);
  }
#undef BLK4
#undef SELADD

  if(n0+0<N) *(float2*)&zrzi[((n0+0)*HID+lane)*2] = make_float2(ar0, ai0);
  if(n0+1<N) *(float2*)&zrzi[((n0+1)*HID+lane)*2] = make_float2(ar1, ai1);
  if(n0+2<N) *(float2*)&zrzi[((n0+2)*HID+lane)*2] = make_float2(ar2, ai2);
  if(n0+3<N) *(float2*)&zrzi[((n0+3)*HID+lane)*2] = make_float2(ar3, ai3);
}

// fused complex dense layer; fp16 LDS + fdot2, merged A/B/C pass.
// 256 thr = 16 o-lanes x 16 grps x 4 nodes; TN=64
__global__ __launch_bounds__(256, 4) void k_dense(
    const float* __restrict__ W1, const float* __restrict__ b1,
    const float* __restrict__ W2, const float* __restrict__ b2,
    const float* __restrict__ zrzi, __half2* __restrict__ hrhi, int N){
  __shared__ __align__(16) __half sW1h[64*HPAD], sW2h[64*HPAD];
  __shared__ __align__(16) __half sZRh[TN*HPAD], sZIh[TN*HPAD];
  int tid = threadIdx.x;
  int o = tid & 15, grp = tid >> 4;
  int node0 = blockIdx.x*TN;
  // stage weights [64][64] fp32 -> fp16
  #pragma unroll
  for(int t=0;t<4;t++){
    int f4 = tid + t*256; int row = f4>>4, kc = f4&15;
    *(uint2*)&sW1h[row*HPAD + kc*4] = pack4(*(const float4*)&W1[row*HID + kc*4]);
    *(uint2*)&sW2h[row*HPAD + kc*4] = pack4(*(const float4*)&W2[row*HID + kc*4]);
  }
  // stage zr/zi: zrzi[node][2k..2k+1] interleaved fp32 -> split fp16 tiles
  #pragma unroll
  for(int t=0;t<8;t++){
    int f4 = tid + t*256;         // 0..2047 over 64 nodes x 32 quads
    int nl = f4 >> 5, q = f4 & 31;
    int node = node0 + nl;
    float4 v = make_float4(0.f,0.f,0.f,0.f);
    if(node<N) v = *(const float4*)&zrzi[node*(2*HID) + q*4];
    __half2 zr2 = __floats2half2_rn(v.x, v.z);   // zr[2q], zr[2q+1]
    __half2 zi2 = __floats2half2_rn(v.y, v.w);   // zi[2q], zi[2q+1]
    *(unsigned*)&sZRh[nl*HPAD + q*2] = *(unsigned*)&zr2;
    *(unsigned*)&sZIh[nl*HPAD + q*2] = *(unsigned*)&zi2;
  }
  __syncthreads();

  float b1v[4], b2v[4];
  #pragma unroll
  for(int r=0;r<4;r++){ b1v[r]=b1[o+16*r]; b2v[r]=b2[o+16*r]; }

  // merged pass A/B/C: accA = zr.W1, accB = zi.W2, accC = zi.W1
  float zrn[4][4], accC[4][4];
  {
    float accA[4][4], accB[4][4];
    #pragma unroll
    for(int r=0;r<4;r++)
      #pragma unroll
      for(int m=0;m<4;m++){ accA[r][m]=0.f; accB[r][m]=0.f; accC[r][m]=0.f; }
    #pragma unroll 2
    for(int c=0;c<8;c++){
      uint4 w1v[4], w2v[4];
      #pragma unroll
      for(int r=0;r<4;r++){
        w1v[r] = *(const uint4*)&sW1h[(o+16*r)*HPAD + c*8];
        w2v[r] = *(const uint4*)&sW2h[(o+16*r)*HPAD + c*8];
      }
      #pragma unroll
      for(int m=0;m<4;m++){
        uint4 xr = *(const uint4*)&sZRh[(grp*4+m)*HPAD + c*8];
        uint4 xi = *(const uint4*)&sZIh[(grp*4+m)*HPAD + c*8];
        #pragma unroll
        for(int r=0;r<4;r++){
          accA[r][m] = dot8h(xr, w1v[r], accA[r][m]);
          accB[r][m] = dot8h(xi, w2v[r], accB[r][m]);
          accC[r][m] = dot8h(xi, w1v[r], accC[r][m]);
        }
      }
    }
    #pragma unroll
    for(int r=0;r<4;r++)
      #pragma unroll
      for(int m=0;m<4;m++)
        zrn[r][m] = accA[r][m] + b1v[r] - accB[r][m] - b2v[r];
  }
  __syncthreads();                 // all reads of sZRh done
  #pragma unroll
  for(int m=0;m<4;m++)
    #pragma unroll
    for(int r=0;r<4;r++)
      sZRh[(grp*4+m)*HPAD + o + 16*r] = __float2half(zrn[r][m]); // pre-relu zrn
  __syncthreads();
  // pass D: accD = zrn . W2
  float accD[4][4];
  #pragma unroll
  for(int r=0;r<4;r++)
    #pragma unroll
    for(int m=0;m<4;m++) accD[r][m]=0.f;
  #pragma unroll 2
  for(int c=0;c<8;c++){
    uint4 w2v[4];
    #pragma unroll
    for(int r=0;r<4;r++)
      w2v[r] = *(const uint4*)&sW2h[(o+16*r)*HPAD + c*8];
    #pragma unroll
    for(int m=0;m<4;m++){
      uint4 x = *(const uint4*)&sZRh[(grp*4+m)*HPAD + c*8];
      #pragma unroll
      for(int r=0;r<4;r++)
        accD[r][m] = dot8h(x, w2v[r], accD[r][m]);
    }
  }
  #pragma unroll
  for(int m=0;m<4;m++){
    int node = node0 + grp*4 + m;
    if(node<N){
      #pragma unroll
      for(int r=0;r<4;r++){
        float zin = accD[r][m] + b2v[r] + accC[r][m] + b1v[r];
        hrhi[node*HID + o + 16*r] =
          __floats2half2_rn(fmaxf(zrn[r][m],0.f), fmaxf(zin,0.f));
      }
    }
  }
}

// logits (128->8) + log_softmax; 8 lanes per node; weights permuted to match
// interleaved (r,i) hrhi layout.
__global__ __launch_bounds__(256) void k_final(
    const __half2* __restrict__ hrhi, const float* __restrict__ t2W,
    const float* __restrict__ t2b, float* __restrict__ out, int N){
  __shared__ float sW[OUTC*132];   // sW[o][2d]=t2W[o][d], sW[o][2d+1]=t2W[o][64+d]
  int tid = threadIdx.x;
  #pragma unroll
  for(int t=0;t<4;t++){
    int idx = tid + t*256;          // 0..1023
    int o2 = idx >> 7, j = idx & 127;
    int dd = j >> 1, part = j & 1;
    sW[o2*132 + j] = t2W[o2*128 + part*64 + dd];
  }
  __syncthreads();
  int o = tid&7, nl = tid>>3;
  int node = blockIdx.x*32 + nl;
  float acc = 0.f;
  if(node<N){
    acc = t2b[o];
    const uint4* hp = reinterpret_cast<const uint4*>(&hrhi[node*HID]);
    #pragma unroll
    for(int q=0;q<16;q++){
      uint4 v = hp[q];              // 4 half2 = dims 4q..4q+3
      __half2 h0 = *reinterpret_cast<__half2*>(&v.x);
      __half2 h1 = *reinterpret_cast<__half2*>(&v.y);
      __half2 h2 = *reinterpret_cast<__half2*>(&v.z);
      __half2 h3 = *reinterpret_cast<__half2*>(&v.w);
      float2 f0 = __half22float2(h0), f1 = __half22float2(h1);
      float2 f2 = __half22float2(h2), f3 = __half22float2(h3);
      float4 w0 = *(const float4*)&sW[o*132 + q*8];
      float4 w1 = *(const float4*)&sW[o*132 + q*8 + 4];
      acc += fmaf(f0.x,w0.x, fmaf(f0.y,w0.y, fmaf(f1.x,w0.z, f1.y*w0.w)));
      acc += fmaf(f2.x,w1.x, fmaf(f2.y,w1.y, fmaf(f3.x,w1.z, f3.y*w1.w)));
    }
  }
  float mx = acc;
  #pragma unroll
  for(int msk=4; msk>=1; msk>>=1) mx = fmaxf(mx, __shfl_xor(mx, msk, 8));
  float e = expf(acc - mx);
  float sm = e;
  #pragma unroll
  for(int msk=4; msk>=1; msk>>=1) sm += __shfl_xor(sm, msk, 8);
  if(node<N) out[node*OUTC+o] = (acc - mx) - logf(sm);
}

extern "C" void kernel_launch(void* const* d_in, const int* in_sizes, int n_in,
                              void* d_out, int out_size, void* d_ws, size_t ws_size,
                              hipStream_t stream) {
  const float* h      = (const float*)d_in[0];
  const float* d      = (const float*)d_in[1];
  const float* w_real = (const float*)d_in[2];
  const float* w_imag = (const float*)d_in[3];
  const float* t1rW   = (const float*)d_in[4];
  const float* t1rb   = (const float*)d_in[5];
  const float* t1iW   = (const float*)d_in[6];
  const float* t1ib   = (const float*)d_in[7];
  const float* W1     = (const float*)d_in[8];
  const float* b1     = (const float*)d_in[9];
  const float* W2     = (const float*)d_in[10];
  const float* b2     = (const float*)d_in[11];
  const float* t2W    = (const float*)d_in[12];
  const float* t2b    = (const float*)d_in[13];
  const int*   src    = (const int*)d_in[14];
  const int*   dst    = (const int*)d_in[15];
  const int N = in_sizes[1];
  const int E = in_sizes[2];
  const int nLayers = in_sizes[8] / (HID*HID);
  float* out = (float*)d_out;

  char* w = (char*)d_ws;
  size_t off = 0;
  auto alloc = [&](size_t bytes)->void*{
    void* p = (void*)(w + off);
    off += (bytes + 255) & ~(size_t)255;
    return p;
  };
  __half2* hrhi   = (__half2*)alloc((size_t)N*HID*sizeof(__half2));
  float*  zrzi    = (float*)alloc((size_t)N*2*HID*4);
  int*    rowptr  = (int*)alloc((size_t)(N+1)*4);
  int*    cnt     = (int*)alloc((size_t)N*4);
  int*    rank    = (int*)alloc((size_t)E*4);
  uint2*  eS      = (uint2*)alloc(((size_t)E + 3*(size_t)N + 8)*8); // padded CSR, 8B payload
  int*    partials= (int*)alloc(2048);

  int nChunks = (N+255)/256;
  int eBlocks = (E+255)/256;
  int nTiles  = (N+TN-1)/TN;
  int aggWaves  = (N+3)/4;                 // 4 nodes per wave
  int aggBlocks = (aggWaves+3)/4;          // 4 waves per 256-thread block

  k_zero<<<nChunks, 256, 0, stream>>>(cnt, N);
  k_hist<<<eBlocks, 256, 0, stream>>>(dst, cnt, rank, E);
  k_scan1<<<nChunks, 256, 0, stream>>>(cnt, rowptr, partials, N);
  k_scan3<<<nChunks, 256, 0, stream>>>(rowptr, partials, N, nChunks);
  k_fillpad<<<nChunks, 256, 0, stream>>>(cnt, rowptr, eS, N);
  k_scatter<<<eBlocks, 256, 0, stream>>>(src, dst, d, w_real, w_imag,
                                         rowptr, rank, eS, E);
  k_transform1<<<nTiles, 256, 0, stream>>>(h, t1rW, t1rb, t1iW, t1ib, hrhi, N);
  for(int i=0;i<nLayers;i++){
    k_agg<<<aggBlocks, 256, 0, stream>>>(rowptr, eS, hrhi, zrzi, N);
    k_dense<<<nTiles, 256, 0, stream>>>(W1 + (size_t)i*HID*HID, b1 + (size_t)i*HID,
                                        W2 + (size_t)i*HID*HID, b2 + (size_t)i*HID,
                                        zrzi, hrhi, N);
  }
  k_final<<<(N+31)/32, 256, 0, stream>>>(hrhi, t2W, t2b, out, N);
}